// Round 2
// baseline (333.446 us; speedup 1.0000x reference)
//
#include <hip/hip_runtime.h>
#include <math.h>

#define NBINS 64
#define HIST_ELEMS (NBINS*NBINS)
#define PTS_PER_BLOCK 1152      // 768 blocks/n * 1152 = 884736 = P; grid 1536 = 6/CU even
#define GXN 768                 // hist blocks per sample
#define CHUNKS 9                // per wave: 1152 / (4 waves * 32)
#define LSTRIDE 68              // col-major lh stride (b128 2-way banks = free)
// weight = exp2(-(u*SQK - b*SQK)^2); SQK = sqrt(8192/63^2*log2(e))
#define SQK 1.7256062f
#define MMB 128                 // minmax blocks per (n,t)
#define RED_BLOCKS 128

typedef float f4 __attribute__((ext_vector_type(4)));
typedef float f2 __attribute__((ext_vector_type(2)));
typedef float f32x4 __attribute__((ext_vector_type(4)));
typedef _Float16 half8 __attribute__((ext_vector_type(8)));
typedef int int4v __attribute__((ext_vector_type(4)));
typedef unsigned int u32x2 __attribute__((ext_vector_type(2)));

static __device__ __forceinline__ half8 pack8(const float* w) {
    int4v v;
    v[0] = __builtin_bit_cast(int, __builtin_amdgcn_cvt_pkrtz(w[0], w[1]));
    v[1] = __builtin_bit_cast(int, __builtin_amdgcn_cvt_pkrtz(w[2], w[3]));
    v[2] = __builtin_bit_cast(int, __builtin_amdgcn_cvt_pkrtz(w[4], w[5]));
    v[3] = __builtin_bit_cast(int, __builtin_amdgcn_cvt_pkrtz(w[6], w[7]));
    return __builtin_bit_cast(half8, v);
}

// packed-f32 math (gfx90a+): 2 f32 lanes per VALU issue
static __device__ __forceinline__ f2 pk_fma(f2 a, f2 b, f2 c) {
    f2 d;
    asm("v_pk_fma_f32 %0, %1, %2, %3" : "=v"(d) : "v"(a), "v"(b), "v"(c));
    return d;
}
static __device__ __forceinline__ f2 pk_mul(f2 a, f2 b) {
    f2 d;
    asm("v_pk_mul_f32 %0, %1, %2" : "=v"(d) : "v"(a), "v"(b));
    return d;
}

// ws layout: pm[1024] floats @0 | unsigned ctr @4096 | float hist[2][4096] @8192
//            | _Float16 bh[2*GXN][4096] @40960
__global__ __launch_bounds__(256) void minmax_kernel(const float* __restrict__ tar,
                                                     const float* __restrict__ src,
                                                     float* __restrict__ pm,
                                                     unsigned* __restrict__ ctr,
                                                     float* __restrict__ hist, int P) {
    const int b = blockIdx.x, n = blockIdx.y, t = blockIdx.z;
    const f4* x = (const f4*)((t == 0 ? tar : src) + (size_t)n * P);
    const int per = (P / 4) / MMB;   // 1728 f4 per block
    float lmin = INFINITY, lmax = -INFINITY;
    for (int i = b * per + threadIdx.x; i < (b + 1) * per; i += 256) {
        f4 v = x[i];
        lmin = fminf(lmin, fminf(fminf(v[0], v[1]), fminf(v[2], v[3])));
        lmax = fmaxf(lmax, fmaxf(fmaxf(v[0], v[1]), fmaxf(v[2], v[3])));
    }
    for (int off = 32; off > 0; off >>= 1) {
        lmin = fminf(lmin, __shfl_down(lmin, off, 64));
        lmax = fmaxf(lmax, __shfl_down(lmax, off, 64));
    }
    __shared__ float smin[4], smax[4];
    const int lane = threadIdx.x & 63, wave = threadIdx.x >> 6;
    if (lane == 0) { smin[wave] = lmin; smax[wave] = lmax; }
    __syncthreads();
    if (threadIdx.x == 0) {
        pm[(n * 2 + t) * MMB + b] =
            fminf(fminf(smin[0], smin[1]), fminf(smin[2], smin[3]));
        pm[512 + (n * 2 + t) * MMB + b] =
            fmaxf(fmaxf(smax[0], smax[1]), fmaxf(smax[2], smax[3]));
    }
    // zero global hist (8192 floats = 2048 f4 over 512 blocks = 4 f4 each) + counter
    const int flat = b + MMB * (n * 2 + t);   // 0..511
    f4* hz = (f4*)hist + flat * 4;
    const f4 z = {0.f, 0.f, 0.f, 0.f};
    if (threadIdx.x < 4) hz[threadIdx.x] = z;
    if (flat == 0 && threadIdx.x == 0) *ctr = 0u;
}

// Joint histogram as 64x64xP GEMM via MFMA f16.  No LDS input staging
// (each wave reads only its own contiguous range; 16-lane broadcast loads
// dedup in the coalescer) -> LDS = lh only (17.4 KB) -> 6 blocks/CU.
// Wave 0 reduces the 128 per-block minmax partials inline; 9 barrier-free
// K=32 chunks/wave; serial-wave NON-ATOMIC combine; private f16 bh tiles.
// A[m][k]: m=lane&15 (+16*mt), k=quad*8+j ; B[k][n]: n=lane&15, k=quad*8+j
// C/D: col=lane&15, row=quad*4+reg -> col-major lh; output TRANSPOSED
// (MI loss is transpose-invariant).
template <int STAGED>
__global__ __launch_bounds__(256, 6) void mfma_hist_kernel(const float* __restrict__ tar,
                                                           const float* __restrict__ src,
                                                           const float* __restrict__ pm,
                                                           _Float16* __restrict__ bh,
                                                           float* __restrict__ hist,
                                                           int P) {
    const int n = blockIdx.y;
    const int bx = blockIdx.x;
    const int tid = threadIdx.x;
    const int lane = tid & 63, wave = tid >> 6;
    const int mlane = lane & 15, quad = lane >> 4;

    __shared__ float lh[NBINS * LSTRIDE];   // col-major: lh[col*LSTRIDE + row]
    __shared__ float mmred[4];

    // --- wave 0: reduce the 128 per-block minmax partials ---
    if (wave == 0) {
        float a = fminf(pm[(n * 2 + 0) * MMB + lane], pm[(n * 2 + 0) * MMB + 64 + lane]);
        float b = fmaxf(pm[512 + (n * 2 + 0) * MMB + lane],
                        pm[512 + (n * 2 + 0) * MMB + 64 + lane]);
        float c = fminf(pm[(n * 2 + 1) * MMB + lane], pm[(n * 2 + 1) * MMB + 64 + lane]);
        float d = fmaxf(pm[512 + (n * 2 + 1) * MMB + lane],
                        pm[512 + (n * 2 + 1) * MMB + 64 + lane]);
        for (int off = 32; off > 0; off >>= 1) {
            a = fminf(a, __shfl_down(a, off, 64));
            b = fmaxf(b, __shfl_down(b, off, 64));
            c = fminf(c, __shfl_down(c, off, 64));
            d = fmaxf(d, __shfl_down(d, off, 64));
        }
        if (lane == 0) { mmred[0] = a; mmred[1] = b; mmred[2] = c; mmred[3] = d; }
    }
    __syncthreads();   // mmred ready

    const float tmin = mmred[0], tmax = mmred[1];
    const float smin = mmred[2], smax = mmred[3];
    const float tk = 63.0f / (tmax - tmin + 1e-10f) * SQK;
    const float sk = 63.0f / (smax - smin + 1e-10f) * SQK;
    const f2 tkk = {tk, tk}, skk = {sk, sk};
    f2 tneg[4], sneg[4];
    #pragma unroll
    for (int mt = 0; mt < 4; ++mt) {
        const float b = SQK * (float)(mlane + 16 * mt);
        const float tb_ = tmin * tk + b;
        const float sb_ = smin * sk + b;
        tneg[mt] = {-tb_, -tb_};
        sneg[mt] = {-sb_, -sb_};
    }

    f32x4 acc[4][4];
    #pragma unroll
    for (int a = 0; a < 4; ++a)
        #pragma unroll
        for (int b = 0; b < 4; ++b) acc[a][b] = (f32x4){0.f, 0.f, 0.f, 0.f};

    // --- compute: wave owns 288 points = 9 chunks of K=32, direct global ---
    const float* tg = tar + (size_t)n * P + (size_t)bx * PTS_PER_BLOCK;
    const float* sg = src + (size_t)n * P + (size_t)bx * PTS_PER_BLOCK;
    const int kwbase = wave * (32 * CHUNKS) + quad * 8;
    #pragma unroll 3
    for (int c = 0; c < CHUNKS; ++c) {
        const int kbase = kwbase + c * 32;
        const f4* pt4 = (const f4*)&tg[kbase];
        const f4* ps4 = (const f4*)&sg[kbase];
        f4 ta = pt4[0], tb = pt4[1];
        f4 sa = ps4[0], sb = ps4[1];
        f2 tp[4], sp[4];
        tp[0] = {ta[0], ta[1]}; tp[1] = {ta[2], ta[3]};
        tp[2] = {tb[0], tb[1]}; tp[3] = {tb[2], tb[3]};
        sp[0] = {sa[0], sa[1]}; sp[1] = {sa[2], sa[3]};
        sp[2] = {sb[0], sb[1]}; sp[3] = {sb[2], sb[3]};

        half8 af[4], bf[4];
        #pragma unroll
        for (int mt = 0; mt < 4; ++mt) {
            float w[8];
            #pragma unroll
            for (int h = 0; h < 4; ++h) {
                f2 d = pk_fma(tp[h], tkk, tneg[mt]);
                f2 s2 = pk_mul(d, d);
                w[2 * h]     = __builtin_amdgcn_exp2f(-s2[0]);
                w[2 * h + 1] = __builtin_amdgcn_exp2f(-s2[1]);
            }
            af[mt] = pack8(w);
        }
        #pragma unroll
        for (int nt = 0; nt < 4; ++nt) {
            float w[8];
            #pragma unroll
            for (int h = 0; h < 4; ++h) {
                f2 d = pk_fma(sp[h], skk, sneg[nt]);
                f2 s2 = pk_mul(d, d);
                w[2 * h]     = __builtin_amdgcn_exp2f(-s2[0]);
                w[2 * h + 1] = __builtin_amdgcn_exp2f(-s2[1]);
            }
            bf[nt] = pack8(w);
        }
        #pragma unroll
        for (int mt = 0; mt < 4; ++mt)
            #pragma unroll
            for (int nt = 0; nt < 4; ++nt)
                acc[mt][nt] = __builtin_amdgcn_mfma_f32_16x16x32_f16(
                    af[mt], bf[nt], acc[mt][nt], 0, 0, 0);
    }

    // --- serial-wave non-atomic combine into col-major lh ---
    #pragma unroll
    for (int w = 0; w < 4; ++w) {
        if (wave == w) {
            #pragma unroll
            for (int nt = 0; nt < 4; ++nt)
                #pragma unroll
                for (int mt = 0; mt < 4; ++mt) {
                    f4* p = (f4*)&lh[(16 * nt + mlane) * LSTRIDE + 16 * mt + 4 * quad];
                    if (w == 0) {
                        *p = acc[mt][nt];
                    } else {
                        f4 v = *p;
                        v += acc[mt][nt];
                        *p = v;
                    }
                }
        }
        __syncthreads();
    }

    if (STAGED) {
        // compact col-major lh -> private dense 4096-entry f16 tile (no atomics)
        u32x2* dst = (u32x2*)(bh + ((size_t)n * GXN + bx) * HIST_ELEMS);
        #pragma unroll
        for (int k = 0; k < 4; ++k) {
            const int i4 = tid + k * 256;          // 0..1023, 4 f16 each
            const int c = i4 >> 4, r4 = (i4 & 15) * 4;
            f4 v = *(const f4*)&lh[c * LSTRIDE + r4];
            u32x2 o;
            o[0] = __builtin_bit_cast(unsigned int, __builtin_amdgcn_cvt_pkrtz(v[0], v[1]));
            o[1] = __builtin_bit_cast(unsigned int, __builtin_amdgcn_cvt_pkrtz(v[2], v[3]));
            dst[i4] = o;
        }
    } else {
        float* gh = hist + (size_t)n * HIST_ELEMS;
        for (int i = tid; i < HIST_ELEMS; i += 256) {
            const int c = i >> 6, r = i & 63;
            unsafeAtomicAdd(&gh[i], lh[c * LSTRIDE + r]);
        }
    }
}

// 128 blocks: block owns 32 u32-columns (64 f16 elems) of one sample;
// 8 threads/column x 96 tiles each, dword loads (coalesced 128B/wave),
// LDS combine, plain store -> hist.  Last-arriving block finalizes.
__global__ __launch_bounds__(256) void reduce_finalize_kernel(const _Float16* __restrict__ bh,
                                                              float* __restrict__ hist,
                                                              unsigned* __restrict__ ctr,
                                                              float* __restrict__ out,
                                                              int staged) {
    const int tid = threadIdx.x;
    const int lane = tid & 63, wave = tid >> 6;
    __shared__ float h2[2 * HIST_ELEMS];
    __shared__ f2 part[256];
    __shared__ float buf[4], rowsum[NBINS], colsum[NBINS], colp[4 * NBINS];
    __shared__ int lastflag;

    if (staged) {
        const int n = blockIdx.x >> 6;          // sample
        const int colgrp = blockIdx.x & 63;     // 32-u32 column group
        const unsigned* bhu = (const unsigned*)bh;
        const int c = colgrp * 32 + (tid & 31);
        const int seg = tid >> 5;               // 0..7
        const unsigned* p = bhu + ((size_t)(n * GXN + seg * (GXN / 8))) * 2048 + c;
        float slo = 0.0f, shi = 0.0f;
        #pragma unroll 8
        for (int k = 0; k < GXN / 8; ++k) {
            unsigned v = p[(size_t)k * 2048];
            union { unsigned u; _Float16 h[2]; } cv; cv.u = v;
            slo += (float)cv.h[0];
            shi += (float)cv.h[1];
        }
        part[tid] = (f2){slo, shi};
        __syncthreads();
        if (tid < 32) {
            f2 s = part[tid];
            #pragma unroll
            for (int j = 1; j < 8; ++j) s += part[tid + 32 * j];
            *(f2*)&hist[(size_t)n * HIST_ELEMS + (colgrp * 32 + tid) * 2] = s;
        }
    }

    __threadfence();
    if (tid == 0) {
        unsigned old = atomicAdd(ctr, 1u);
        lastflag = (old == RED_BLOCKS - 1) ? 1 : 0;
    }
    __syncthreads();
    if (!lastflag) return;

    // system-scope loads: bypass per-XCD L2 (writers fenced via threadfence)
    for (int i = tid; i < 2 * HIST_ELEMS; i += 256)
        h2[i] = __hip_atomic_load(&hist[i], __ATOMIC_RELAXED, __HIP_MEMORY_SCOPE_SYSTEM);
    __syncthreads();

    float accl = 0.0f;
    for (int nn = 0; nn < 2; ++nn) {
        const float* h = h2 + nn * HIST_ELEMS;
        {
            int r = tid >> 2, q = tid & 3;
            const float* hp = h + r * NBINS + q * 16;
            float sv = 0.0f;
            #pragma unroll
            for (int k = 0; k < 16; ++k) sv += hp[k];
            sv += __shfl_down(sv, 1, 64);
            sv += __shfl_down(sv, 2, 64);
            if (q == 0) rowsum[r] = sv;
        }
        {
            int c = tid & 63, g = tid >> 6;
            const float* hp = h + (g * 16) * NBINS + c;
            float sv = 0.0f;
            #pragma unroll
            for (int k = 0; k < 16; ++k) sv += hp[k * NBINS];
            colp[g * NBINS + c] = sv;
        }
        __syncthreads();
        if (tid < NBINS)
            colsum[tid] = colp[0 * NBINS + tid] + colp[1 * NBINS + tid] +
                          colp[2 * NBINS + tid] + colp[3 * NBINS + tid];
        __syncthreads();

        float tv = (tid < NBINS) ? rowsum[tid] : 0.0f;
        for (int off = 32; off > 0; off >>= 1) tv += __shfl_down(tv, off, 64);
        __syncthreads();
        if (lane == 0) buf[wave] = tv;
        __syncthreads();
        const float total = buf[0] + buf[1] + buf[2] + buf[3];
        const float inv = 1.0f / total;

        float ej = 0.0f;
        for (int i = tid; i < HIST_ELEMS; i += 256) {
            float p = h[i] * inv;
            ej += p * __logf(p + 1e-10f);
        }
        for (int off = 32; off > 0; off >>= 1) ej += __shfl_down(ej, off, 64);
        __syncthreads();
        if (lane == 0) buf[wave] = ej;
        __syncthreads();
        const float entj = -(buf[0] + buf[1] + buf[2] + buf[3]);

        float em = 0.0f;
        if (tid < NBINS) {
            float p = rowsum[tid] * inv;
            em = p * __logf(p + 1e-10f);
        } else if (tid < 2 * NBINS) {
            float p = colsum[tid - NBINS] * inv;
            em = p * __logf(p + 1e-10f);
        }
        for (int off = 32; off > 0; off >>= 1) em += __shfl_down(em, off, 64);
        __syncthreads();
        if (lane == 0) buf[wave] = em;
        __syncthreads();
        const float ents = -(buf[0] + buf[1] + buf[2] + buf[3]);

        accl += ents / entj;
        __syncthreads();
    }
    if (tid == 0) out[0] = -0.5f * accl;
}

extern "C" void kernel_launch(void* const* d_in, const int* in_sizes, int n_in,
                              void* d_out, int out_size, void* d_ws, size_t ws_size,
                              hipStream_t stream) {
    const float* tar = (const float*)d_in[0];
    const float* src = (const float*)d_in[1];
    const int N = 2;
    const int P = in_sizes[0] / N;  // 884736

    float* pm = (float*)d_ws;
    unsigned* ctr = (unsigned*)((char*)d_ws + 4096);
    float* hist = (float*)((char*)d_ws + 8192);
    _Float16* bh = (_Float16*)((char*)d_ws + 40960);
    float* out = (float*)d_out;

    const size_t need = 40960 + (size_t)2 * GXN * HIST_ELEMS * sizeof(_Float16); // ~12.6 MB

    minmax_kernel<<<dim3(MMB, N, 2), 256, 0, stream>>>(tar, src, pm, ctr, hist, P);
    if (ws_size >= need) {
        mfma_hist_kernel<1><<<dim3(GXN, N), 256, 0, stream>>>(tar, src, pm, bh, hist, P);
        reduce_finalize_kernel<<<RED_BLOCKS, 256, 0, stream>>>(bh, hist, ctr, out, 1);
    } else {
        mfma_hist_kernel<0><<<dim3(GXN, N), 256, 0, stream>>>(tar, src, pm, bh, hist, P);
        reduce_finalize_kernel<<<RED_BLOCKS, 256, 0, stream>>>(bh, hist, ctr, out, 0);
    }
}

// Round 3
// 329.256 us; speedup vs baseline: 1.0127x; 1.0127x over previous
//
#include <hip/hip_runtime.h>
#include <math.h>

#define NBINS 64
#define HIST_ELEMS (NBINS*NBINS)
#define GXN 864                 // hist blocks per sample; grid 1728 ~ 6.75/CU, all co-resident
#define PTS_PER_BLOCK 1024      // 864 * 1024 = 884736 = P; 256 f4 per tensor per block
// bin-unit Gaussian: w = exp2(-((u - b)*SQK)^2), SQK = sqrt(8192/63^2*log2(e))
#define SQK 1.7256062f
#define MMB 128                 // minmax blocks per (n,t)
#define RED_BLOCKS 128
#define TILES_PER_SEG (GXN/8)   // 108

typedef float f4 __attribute__((ext_vector_type(4)));
typedef float f2 __attribute__((ext_vector_type(2)));
typedef unsigned int u32x2 __attribute__((ext_vector_type(2)));

// ws layout: pm[1024] floats @0 | unsigned ctr @4096 | float hist[2][4096] @8192
//            | _Float16 bh[2*GXN][4096] @40960
__global__ __launch_bounds__(256) void minmax_kernel(const float* __restrict__ tar,
                                                     const float* __restrict__ src,
                                                     float* __restrict__ pm,
                                                     unsigned* __restrict__ ctr,
                                                     float* __restrict__ hist, int P) {
    const int b = blockIdx.x, n = blockIdx.y, t = blockIdx.z;
    const f4* x = (const f4*)((t == 0 ? tar : src) + (size_t)n * P);
    const int per = (P / 4) / MMB;   // 1728 f4 per block
    float lmin = INFINITY, lmax = -INFINITY;
    for (int i = b * per + threadIdx.x; i < (b + 1) * per; i += 256) {
        f4 v = x[i];
        lmin = fminf(lmin, fminf(fminf(v[0], v[1]), fminf(v[2], v[3])));
        lmax = fmaxf(lmax, fmaxf(fmaxf(v[0], v[1]), fmaxf(v[2], v[3])));
    }
    for (int off = 32; off > 0; off >>= 1) {
        lmin = fminf(lmin, __shfl_down(lmin, off, 64));
        lmax = fmaxf(lmax, __shfl_down(lmax, off, 64));
    }
    __shared__ float smin[4], smax[4];
    const int lane = threadIdx.x & 63, wave = threadIdx.x >> 6;
    if (lane == 0) { smin[wave] = lmin; smax[wave] = lmax; }
    __syncthreads();
    if (threadIdx.x == 0) {
        pm[(n * 2 + t) * MMB + b] =
            fminf(fminf(smin[0], smin[1]), fminf(smin[2], smin[3]));
        pm[512 + (n * 2 + t) * MMB + b] =
            fmaxf(fmaxf(smax[0], smax[1]), fmaxf(smax[2], smax[3]));
    }
    // zero global hist (8192 floats = 2048 f4 over 512 blocks = 4 f4 each) + counter
    const int flat = b + MMB * (n * 2 + t);   // 0..511
    f4* hz = (f4*)hist + flat * 4;
    const f4 z = {0.f, 0.f, 0.f, 0.f};
    if (threadIdx.x < 4) hz[threadIdx.x] = z;
    if (flat == 0 && threadIdx.x == 0) *ctr = 0u;
}

// Sparse scatter joint-histogram.  sigma = 0.49 bins -> only the 5x5 bin
// window around each (t,s) point carries weight >= 2.5e-6; everything else
// underflows even f16.  Each point: 2 fma + 2 round + 10 exp2 + 25 mul +
// 25 ds_add_f32 (immediate offsets off one base; bank = (sb0+j)%32, random
// sb0 -> ~2-way = free).  ~40 VGPR, 16.4 KB LDS -> whole grid co-resident.
// lh is row-major [tbin][sbin]; MI loss is transpose-invariant anyway.
template <int STAGED>
__global__ __launch_bounds__(256) void scatter_hist_kernel(const float* __restrict__ tar,
                                                           const float* __restrict__ src,
                                                           const float* __restrict__ pm,
                                                           _Float16* __restrict__ bh,
                                                           float* __restrict__ hist,
                                                           int P) {
    const int n = blockIdx.y;
    const int bx = blockIdx.x;
    const int tid = threadIdx.x;
    const int lane = tid & 63, wave = tid >> 6;

    __shared__ float lh[HIST_ELEMS];
    __shared__ float mmred[4];

    // --- wave 0: reduce the 128 per-block minmax partials ---
    if (wave == 0) {
        float a = fminf(pm[(n * 2 + 0) * MMB + lane], pm[(n * 2 + 0) * MMB + 64 + lane]);
        float b = fmaxf(pm[512 + (n * 2 + 0) * MMB + lane],
                        pm[512 + (n * 2 + 0) * MMB + 64 + lane]);
        float c = fminf(pm[(n * 2 + 1) * MMB + lane], pm[(n * 2 + 1) * MMB + 64 + lane]);
        float d = fmaxf(pm[512 + (n * 2 + 1) * MMB + lane],
                        pm[512 + (n * 2 + 1) * MMB + 64 + lane]);
        for (int off = 32; off > 0; off >>= 1) {
            a = fminf(a, __shfl_down(a, off, 64));
            b = fmaxf(b, __shfl_down(b, off, 64));
            c = fminf(c, __shfl_down(c, off, 64));
            d = fmaxf(d, __shfl_down(d, off, 64));
        }
        if (lane == 0) { mmred[0] = a; mmred[1] = b; mmred[2] = c; mmred[3] = d; }
    }
    // --- zero lh: 1024 f4 over 256 threads ---
    {
        f4* lz = (f4*)lh;
        const f4 z = {0.f, 0.f, 0.f, 0.f};
        #pragma unroll
        for (int k = 0; k < 4; ++k) lz[tid + k * 256] = z;
    }
    __syncthreads();   // mmred + zero complete

    const float tmin = mmred[0], tmax = mmred[1];
    const float smin = mmred[2], smax = mmred[3];
    const float tk = 63.0f / (tmax - tmin + 1e-10f);
    const float sk = 63.0f / (smax - smin + 1e-10f);
    const float toff = -tmin * tk;
    const float soff = -smin * sk;

    auto process = [&](float xt, float xs) {
        const float ut = fmaf(xt, tk, toff);          // bin units, [0,63]
        const float us = fmaf(xs, sk, soff);
        const int ib = (int)rintf(ut);
        const int jb = (int)rintf(us);
        const int tb0 = min(max(ib - 2, 0), 59);
        const int sb0 = min(max(jb - 2, 0), 59);
        const float dt0 = (ut - (float)tb0) * SQK;
        const float ds0 = (us - (float)sb0) * SQK;
        float wt[5], ws[5];
        #pragma unroll
        for (int i = 0; i < 5; ++i) {
            const float a = dt0 - (float)i * SQK;
            const float b = ds0 - (float)i * SQK;
            wt[i] = __builtin_amdgcn_exp2f(-(a * a));
            ws[i] = __builtin_amdgcn_exp2f(-(b * b));
        }
        const int base = tb0 * NBINS + sb0;
        #pragma unroll
        for (int i = 0; i < 5; ++i)
            #pragma unroll
            for (int j = 0; j < 5; ++j)
                atomicAdd(&lh[base + i * NBINS + j], wt[i] * ws[j]);
    };

    // --- each thread: one f4 per tensor = 4 points, perfectly coalesced ---
    {
        const f4* tg4 = (const f4*)(tar + (size_t)n * P + (size_t)bx * PTS_PER_BLOCK);
        const f4* sg4 = (const f4*)(src + (size_t)n * P + (size_t)bx * PTS_PER_BLOCK);
        const f4 xt = tg4[tid];
        const f4 xs = sg4[tid];
        #pragma unroll
        for (int j = 0; j < 4; ++j) process(xt[j], xs[j]);
    }
    __syncthreads();   // all ds_add complete

    if (STAGED) {
        // pack dense row-major lh -> private 4096-entry f16 tile (no atomics)
        u32x2* dst = (u32x2*)(bh + ((size_t)n * GXN + bx) * HIST_ELEMS);
        #pragma unroll
        for (int k = 0; k < 4; ++k) {
            const int i4 = tid + k * 256;          // 0..1023, 4 floats each
            f4 v = *(const f4*)&lh[i4 * 4];
            u32x2 o;
            o[0] = __builtin_bit_cast(unsigned int, __builtin_amdgcn_cvt_pkrtz(v[0], v[1]));
            o[1] = __builtin_bit_cast(unsigned int, __builtin_amdgcn_cvt_pkrtz(v[2], v[3]));
            dst[i4] = o;
        }
    } else {
        float* gh = hist + (size_t)n * HIST_ELEMS;
        for (int i = tid; i < HIST_ELEMS; i += 256)
            unsafeAtomicAdd(&gh[i], lh[i]);
    }
}

// 128 blocks: block owns 32 u32-columns (64 f16 elems) of one sample;
// 8 segs x 108 tiles each, dword loads (coalesced 128B/wave),
// LDS combine, plain store -> hist.  Last-arriving block finalizes.
__global__ __launch_bounds__(256) void reduce_finalize_kernel(const _Float16* __restrict__ bh,
                                                              float* __restrict__ hist,
                                                              unsigned* __restrict__ ctr,
                                                              float* __restrict__ out,
                                                              int staged) {
    const int tid = threadIdx.x;
    const int lane = tid & 63, wave = tid >> 6;
    __shared__ float h2[2 * HIST_ELEMS];
    __shared__ f2 part[256];
    __shared__ float buf[4], rowsum[NBINS], colsum[NBINS], colp[4 * NBINS];
    __shared__ int lastflag;

    if (staged) {
        const int n = blockIdx.x >> 6;          // sample
        const int colgrp = blockIdx.x & 63;     // 32-u32 column group
        const unsigned* bhu = (const unsigned*)bh;
        const int c = colgrp * 32 + (tid & 31);
        const int seg = tid >> 5;               // 0..7
        const unsigned* p = bhu + ((size_t)(n * GXN + seg * TILES_PER_SEG)) * 2048 + c;
        float slo = 0.0f, shi = 0.0f;
        #pragma unroll 4
        for (int k = 0; k < TILES_PER_SEG; ++k) {
            unsigned v = p[(size_t)k * 2048];
            union { unsigned u; _Float16 h[2]; } cv; cv.u = v;
            slo += (float)cv.h[0];
            shi += (float)cv.h[1];
        }
        part[tid] = (f2){slo, shi};
        __syncthreads();
        if (tid < 32) {
            f2 s = part[tid];
            #pragma unroll
            for (int j = 1; j < 8; ++j) s += part[tid + 32 * j];
            *(f2*)&hist[(size_t)n * HIST_ELEMS + (colgrp * 32 + tid) * 2] = s;
        }
    }

    __threadfence();
    if (tid == 0) {
        unsigned old = atomicAdd(ctr, 1u);
        lastflag = (old == RED_BLOCKS - 1) ? 1 : 0;
    }
    __syncthreads();
    if (!lastflag) return;

    // system-scope loads: bypass per-XCD L2 (writers fenced via threadfence)
    for (int i = tid; i < 2 * HIST_ELEMS; i += 256)
        h2[i] = __hip_atomic_load(&hist[i], __ATOMIC_RELAXED, __HIP_MEMORY_SCOPE_SYSTEM);
    __syncthreads();

    float accl = 0.0f;
    for (int nn = 0; nn < 2; ++nn) {
        const float* h = h2 + nn * HIST_ELEMS;
        {
            int r = tid >> 2, q = tid & 3;
            const float* hp = h + r * NBINS + q * 16;
            float sv = 0.0f;
            #pragma unroll
            for (int k = 0; k < 16; ++k) sv += hp[k];
            sv += __shfl_down(sv, 1, 64);
            sv += __shfl_down(sv, 2, 64);
            if (q == 0) rowsum[r] = sv;
        }
        {
            int c = tid & 63, g = tid >> 6;
            const float* hp = h + (g * 16) * NBINS + c;
            float sv = 0.0f;
            #pragma unroll
            for (int k = 0; k < 16; ++k) sv += hp[k * NBINS];
            colp[g * NBINS + c] = sv;
        }
        __syncthreads();
        if (tid < NBINS)
            colsum[tid] = colp[0 * NBINS + tid] + colp[1 * NBINS + tid] +
                          colp[2 * NBINS + tid] + colp[3 * NBINS + tid];
        __syncthreads();

        float tv = (tid < NBINS) ? rowsum[tid] : 0.0f;
        for (int off = 32; off > 0; off >>= 1) tv += __shfl_down(tv, off, 64);
        __syncthreads();
        if (lane == 0) buf[wave] = tv;
        __syncthreads();
        const float total = buf[0] + buf[1] + buf[2] + buf[3];
        const float inv = 1.0f / total;

        float ej = 0.0f;
        for (int i = tid; i < HIST_ELEMS; i += 256) {
            float p = h[i] * inv;
            ej += p * __logf(p + 1e-10f);
        }
        for (int off = 32; off > 0; off >>= 1) ej += __shfl_down(ej, off, 64);
        __syncthreads();
        if (lane == 0) buf[wave] = ej;
        __syncthreads();
        const float entj = -(buf[0] + buf[1] + buf[2] + buf[3]);

        float em = 0.0f;
        if (tid < NBINS) {
            float p = rowsum[tid] * inv;
            em = p * __logf(p + 1e-10f);
        } else if (tid < 2 * NBINS) {
            float p = colsum[tid - NBINS] * inv;
            em = p * __logf(p + 1e-10f);
        }
        for (int off = 32; off > 0; off >>= 1) em += __shfl_down(em, off, 64);
        __syncthreads();
        if (lane == 0) buf[wave] = em;
        __syncthreads();
        const float ents = -(buf[0] + buf[1] + buf[2] + buf[3]);

        accl += ents / entj;
        __syncthreads();
    }
    if (tid == 0) out[0] = -0.5f * accl;
}

extern "C" void kernel_launch(void* const* d_in, const int* in_sizes, int n_in,
                              void* d_out, int out_size, void* d_ws, size_t ws_size,
                              hipStream_t stream) {
    const float* tar = (const float*)d_in[0];
    const float* src = (const float*)d_in[1];
    const int N = 2;
    const int P = in_sizes[0] / N;  // 884736

    float* pm = (float*)d_ws;
    unsigned* ctr = (unsigned*)((char*)d_ws + 4096);
    float* hist = (float*)((char*)d_ws + 8192);
    _Float16* bh = (_Float16*)((char*)d_ws + 40960);
    float* out = (float*)d_out;

    const size_t need = 40960 + (size_t)2 * GXN * HIST_ELEMS * sizeof(_Float16); // ~14.2 MB

    minmax_kernel<<<dim3(MMB, N, 2), 256, 0, stream>>>(tar, src, pm, ctr, hist, P);
    if (ws_size >= need) {
        scatter_hist_kernel<1><<<dim3(GXN, N), 256, 0, stream>>>(tar, src, pm, bh, hist, P);
        reduce_finalize_kernel<<<RED_BLOCKS, 256, 0, stream>>>(bh, hist, ctr, out, 1);
    } else {
        scatter_hist_kernel<0><<<dim3(GXN, N), 256, 0, stream>>>(tar, src, pm, bh, hist, P);
        reduce_finalize_kernel<<<RED_BLOCKS, 256, 0, stream>>>(bh, hist, ctr, out, 0);
    }
}

// Round 4
// 328.224 us; speedup vs baseline: 1.0159x; 1.0031x over previous
//
#include <hip/hip_runtime.h>
#include <math.h>

#define NBINS 64
#define HIST_ELEMS (NBINS*NBINS)
#define GXN 864                 // hist blocks per sample; grid 1728 ~ 6.75/CU, all co-resident
#define PTS_PER_BLOCK 1024      // 864 * 1024 = 884736 = P; 256 f4 per tensor per block
// bin-unit Gaussian: w = exp2(-((u - b)*SQK)^2), SQK = sqrt(8192/63^2*log2(e))
#define SQK 1.7256062f
#define MMB 128                 // minmax blocks per (n,t)
#define RED_BLOCKS 128
#define TILES_PER_SEG (GXN/8)   // 108

typedef float f4 __attribute__((ext_vector_type(4)));
typedef float f2 __attribute__((ext_vector_type(2)));
typedef unsigned int u32x2 __attribute__((ext_vector_type(2)));

// ws layout: pm[1024] floats @0 | unsigned ctr @4096 | float hist[2][4096] @8192
//            | _Float16 bh[2*GXN][4096] @40960
__global__ __launch_bounds__(256) void minmax_kernel(const float* __restrict__ tar,
                                                     const float* __restrict__ src,
                                                     float* __restrict__ pm,
                                                     unsigned* __restrict__ ctr,
                                                     float* __restrict__ hist, int P) {
    const int b = blockIdx.x, n = blockIdx.y, t = blockIdx.z;
    const f4* x = (const f4*)((t == 0 ? tar : src) + (size_t)n * P);
    const int per = (P / 4) / MMB;   // 1728 f4 per block
    float lmin = INFINITY, lmax = -INFINITY;
    for (int i = b * per + threadIdx.x; i < (b + 1) * per; i += 256) {
        f4 v = x[i];
        lmin = fminf(lmin, fminf(fminf(v[0], v[1]), fminf(v[2], v[3])));
        lmax = fmaxf(lmax, fmaxf(fmaxf(v[0], v[1]), fmaxf(v[2], v[3])));
    }
    for (int off = 32; off > 0; off >>= 1) {
        lmin = fminf(lmin, __shfl_down(lmin, off, 64));
        lmax = fmaxf(lmax, __shfl_down(lmax, off, 64));
    }
    __shared__ float smin[4], smax[4];
    const int lane = threadIdx.x & 63, wave = threadIdx.x >> 6;
    if (lane == 0) { smin[wave] = lmin; smax[wave] = lmax; }
    __syncthreads();
    if (threadIdx.x == 0) {
        pm[(n * 2 + t) * MMB + b] =
            fminf(fminf(smin[0], smin[1]), fminf(smin[2], smin[3]));
        pm[512 + (n * 2 + t) * MMB + b] =
            fmaxf(fmaxf(smax[0], smax[1]), fmaxf(smax[2], smax[3]));
    }
    // zero global hist (8192 floats = 2048 f4 over 512 blocks = 4 f4 each) + counter
    const int flat = b + MMB * (n * 2 + t);   // 0..511
    f4* hz = (f4*)hist + flat * 4;
    const f4 z = {0.f, 0.f, 0.f, 0.f};
    if (threadIdx.x < 4) hz[threadIdx.x] = z;
    if (flat == 0 && threadIdx.x == 0) *ctr = 0u;
}

// Sparse scatter joint-histogram.  sigma = 0.49 bins -> only the 5x5 bin
// window around each (t,s) pair carries weight >= 2.5e-6.  Each pair:
// 2 fma + 2 round + 10 exp2 + 25 mul + 25 ds_add_f32.
// CRITICAL: plain atomicAdd on LDS floats lowers to a safe-FP CAS loop
// (round-3: 233us, VALUBusy 1.9%).  We emit the HW instruction directly:
// ds_add_f32 with one VGPR base (low 32 bits of the generic pointer =
// workgroup-relative LDS byte offset) + 25 compile-time offset: immediates.
// ~40 VGPR, 16.4 KB LDS -> whole grid co-resident.  lh row-major [t][s];
// MI loss is transpose-invariant.
template <int STAGED>
__global__ __launch_bounds__(256) void scatter_hist_kernel(const float* __restrict__ tar,
                                                           const float* __restrict__ src,
                                                           const float* __restrict__ pm,
                                                           _Float16* __restrict__ bh,
                                                           float* __restrict__ hist,
                                                           int P) {
    const int n = blockIdx.y;
    const int bx = blockIdx.x;
    const int tid = threadIdx.x;
    const int lane = tid & 63, wave = tid >> 6;

    __shared__ float lh[HIST_ELEMS];
    __shared__ float mmred[4];

    // --- wave 0: reduce the 128 per-block minmax partials ---
    if (wave == 0) {
        float a = fminf(pm[(n * 2 + 0) * MMB + lane], pm[(n * 2 + 0) * MMB + 64 + lane]);
        float b = fmaxf(pm[512 + (n * 2 + 0) * MMB + lane],
                        pm[512 + (n * 2 + 0) * MMB + 64 + lane]);
        float c = fminf(pm[(n * 2 + 1) * MMB + lane], pm[(n * 2 + 1) * MMB + 64 + lane]);
        float d = fmaxf(pm[512 + (n * 2 + 1) * MMB + lane],
                        pm[512 + (n * 2 + 1) * MMB + 64 + lane]);
        for (int off = 32; off > 0; off >>= 1) {
            a = fminf(a, __shfl_down(a, off, 64));
            b = fmaxf(b, __shfl_down(b, off, 64));
            c = fminf(c, __shfl_down(c, off, 64));
            d = fmaxf(d, __shfl_down(d, off, 64));
        }
        if (lane == 0) { mmred[0] = a; mmred[1] = b; mmred[2] = c; mmred[3] = d; }
    }
    // --- zero lh: 1024 f4 over 256 threads ---
    {
        f4* lz = (f4*)lh;
        const f4 z = {0.f, 0.f, 0.f, 0.f};
        #pragma unroll
        for (int k = 0; k < 4; ++k) lz[tid + k * 256] = z;
    }
    __syncthreads();   // mmred + zero complete

    const float tmin = mmred[0], tmax = mmred[1];
    const float smin = mmred[2], smax = mmred[3];
    const float tk = 63.0f / (tmax - tmin + 1e-10f);
    const float sk = 63.0f / (smax - smin + 1e-10f);
    const float toff = -tmin * tk;
    const float soff = -smin * sk;

    // workgroup-relative LDS byte offset of lh (low 32 bits of generic ptr)
    const unsigned lds_base = (unsigned)(size_t)(void*)lh;

#define DSADD(VAL, OFFSTR) \
    asm volatile("ds_add_f32 %0, %1 offset:" OFFSTR :: "v"(a0), "v"(VAL))

    auto process = [&](float xt, float xs) {
        const float ut = fmaf(xt, tk, toff);          // bin units, [0,63]
        const float us = fmaf(xs, sk, soff);
        const int ib = (int)rintf(ut);
        const int jb = (int)rintf(us);
        const int tb0 = min(max(ib - 2, 0), 59);
        const int sb0 = min(max(jb - 2, 0), 59);
        const float dt0 = (ut - (float)tb0) * SQK;
        const float ds0 = (us - (float)sb0) * SQK;
        float wt[5], ws[5];
        #pragma unroll
        for (int i = 0; i < 5; ++i) {
            const float a = dt0 - (float)i * SQK;
            const float b = ds0 - (float)i * SQK;
            wt[i] = __builtin_amdgcn_exp2f(-(a * a));
            ws[i] = __builtin_amdgcn_exp2f(-(b * b));
        }
        const unsigned a0 = lds_base + (unsigned)(((tb0 << 6) + sb0) << 2);
        DSADD(wt[0] * ws[0], "0");    DSADD(wt[0] * ws[1], "4");
        DSADD(wt[0] * ws[2], "8");    DSADD(wt[0] * ws[3], "12");
        DSADD(wt[0] * ws[4], "16");
        DSADD(wt[1] * ws[0], "256");  DSADD(wt[1] * ws[1], "260");
        DSADD(wt[1] * ws[2], "264");  DSADD(wt[1] * ws[3], "268");
        DSADD(wt[1] * ws[4], "272");
        DSADD(wt[2] * ws[0], "512");  DSADD(wt[2] * ws[1], "516");
        DSADD(wt[2] * ws[2], "520");  DSADD(wt[2] * ws[3], "524");
        DSADD(wt[2] * ws[4], "528");
        DSADD(wt[3] * ws[0], "768");  DSADD(wt[3] * ws[1], "772");
        DSADD(wt[3] * ws[2], "776");  DSADD(wt[3] * ws[3], "780");
        DSADD(wt[3] * ws[4], "784");
        DSADD(wt[4] * ws[0], "1024"); DSADD(wt[4] * ws[1], "1028");
        DSADD(wt[4] * ws[2], "1032"); DSADD(wt[4] * ws[3], "1036");
        DSADD(wt[4] * ws[4], "1040");
    };
#undef DSADD

    // --- each thread: one f4 per tensor = 4 pairs, perfectly coalesced ---
    {
        const f4* tg4 = (const f4*)(tar + (size_t)n * P + (size_t)bx * PTS_PER_BLOCK);
        const f4* sg4 = (const f4*)(src + (size_t)n * P + (size_t)bx * PTS_PER_BLOCK);
        const f4 xt = tg4[tid];
        const f4 xs = sg4[tid];
        #pragma unroll
        for (int j = 0; j < 4; ++j) process(xt[j], xs[j]);
    }
    // drain asm-issued ds_add ops (compiler doesn't track them), then barrier
    asm volatile("s_waitcnt lgkmcnt(0)" ::: "memory");
    __syncthreads();   // all waves' atomics complete

    if (STAGED) {
        // pack dense row-major lh -> private 4096-entry f16 tile (no atomics)
        u32x2* dst = (u32x2*)(bh + ((size_t)n * GXN + bx) * HIST_ELEMS);
        #pragma unroll
        for (int k = 0; k < 4; ++k) {
            const int i4 = tid + k * 256;          // 0..1023, 4 floats each
            f4 v = *(const f4*)&lh[i4 * 4];
            u32x2 o;
            o[0] = __builtin_bit_cast(unsigned int, __builtin_amdgcn_cvt_pkrtz(v[0], v[1]));
            o[1] = __builtin_bit_cast(unsigned int, __builtin_amdgcn_cvt_pkrtz(v[2], v[3]));
            dst[i4] = o;
        }
    } else {
        float* gh = hist + (size_t)n * HIST_ELEMS;
        for (int i = tid; i < HIST_ELEMS; i += 256)
            unsafeAtomicAdd(&gh[i], lh[i]);
    }
}

// 128 blocks: block owns 32 u32-columns (64 f16 elems) of one sample;
// 8 segs x 108 tiles each, dword loads (coalesced 128B/wave),
// LDS combine, plain store -> hist.  Last-arriving block finalizes.
__global__ __launch_bounds__(256) void reduce_finalize_kernel(const _Float16* __restrict__ bh,
                                                              float* __restrict__ hist,
                                                              unsigned* __restrict__ ctr,
                                                              float* __restrict__ out,
                                                              int staged) {
    const int tid = threadIdx.x;
    const int lane = tid & 63, wave = tid >> 6;
    __shared__ float h2[2 * HIST_ELEMS];
    __shared__ f2 part[256];
    __shared__ float buf[4], rowsum[NBINS], colsum[NBINS], colp[4 * NBINS];
    __shared__ int lastflag;

    if (staged) {
        const int n = blockIdx.x >> 6;          // sample
        const int colgrp = blockIdx.x & 63;     // 32-u32 column group
        const unsigned* bhu = (const unsigned*)bh;
        const int c = colgrp * 32 + (tid & 31);
        const int seg = tid >> 5;               // 0..7
        const unsigned* p = bhu + ((size_t)(n * GXN + seg * TILES_PER_SEG)) * 2048 + c;
        float slo = 0.0f, shi = 0.0f;
        #pragma unroll 4
        for (int k = 0; k < TILES_PER_SEG; ++k) {
            unsigned v = p[(size_t)k * 2048];
            union { unsigned u; _Float16 h[2]; } cv; cv.u = v;
            slo += (float)cv.h[0];
            shi += (float)cv.h[1];
        }
        part[tid] = (f2){slo, shi};
        __syncthreads();
        if (tid < 32) {
            f2 s = part[tid];
            #pragma unroll
            for (int j = 1; j < 8; ++j) s += part[tid + 32 * j];
            *(f2*)&hist[(size_t)n * HIST_ELEMS + (colgrp * 32 + tid) * 2] = s;
        }
    }

    __threadfence();
    if (tid == 0) {
        unsigned old = atomicAdd(ctr, 1u);
        lastflag = (old == RED_BLOCKS - 1) ? 1 : 0;
    }
    __syncthreads();
    if (!lastflag) return;

    // system-scope loads: bypass per-XCD L2 (writers fenced via threadfence)
    for (int i = tid; i < 2 * HIST_ELEMS; i += 256)
        h2[i] = __hip_atomic_load(&hist[i], __ATOMIC_RELAXED, __HIP_MEMORY_SCOPE_SYSTEM);
    __syncthreads();

    float accl = 0.0f;
    for (int nn = 0; nn < 2; ++nn) {
        const float* h = h2 + nn * HIST_ELEMS;
        {
            int r = tid >> 2, q = tid & 3;
            const float* hp = h + r * NBINS + q * 16;
            float sv = 0.0f;
            #pragma unroll
            for (int k = 0; k < 16; ++k) sv += hp[k];
            sv += __shfl_down(sv, 1, 64);
            sv += __shfl_down(sv, 2, 64);
            if (q == 0) rowsum[r] = sv;
        }
        {
            int c = tid & 63, g = tid >> 6;
            const float* hp = h + (g * 16) * NBINS + c;
            float sv = 0.0f;
            #pragma unroll
            for (int k = 0; k < 16; ++k) sv += hp[k * NBINS];
            colp[g * NBINS + c] = sv;
        }
        __syncthreads();
        if (tid < NBINS)
            colsum[tid] = colp[0 * NBINS + tid] + colp[1 * NBINS + tid] +
                          colp[2 * NBINS + tid] + colp[3 * NBINS + tid];
        __syncthreads();

        float tv = (tid < NBINS) ? rowsum[tid] : 0.0f;
        for (int off = 32; off > 0; off >>= 1) tv += __shfl_down(tv, off, 64);
        __syncthreads();
        if (lane == 0) buf[wave] = tv;
        __syncthreads();
        const float total = buf[0] + buf[1] + buf[2] + buf[3];
        const float inv = 1.0f / total;

        float ej = 0.0f;
        for (int i = tid; i < HIST_ELEMS; i += 256) {
            float p = h[i] * inv;
            ej += p * __logf(p + 1e-10f);
        }
        for (int off = 32; off > 0; off >>= 1) ej += __shfl_down(ej, off, 64);
        __syncthreads();
        if (lane == 0) buf[wave] = ej;
        __syncthreads();
        const float entj = -(buf[0] + buf[1] + buf[2] + buf[3]);

        float em = 0.0f;
        if (tid < NBINS) {
            float p = rowsum[tid] * inv;
            em = p * __logf(p + 1e-10f);
        } else if (tid < 2 * NBINS) {
            float p = colsum[tid - NBINS] * inv;
            em = p * __logf(p + 1e-10f);
        }
        for (int off = 32; off > 0; off >>= 1) em += __shfl_down(em, off, 64);
        __syncthreads();
        if (lane == 0) buf[wave] = em;
        __syncthreads();
        const float ents = -(buf[0] + buf[1] + buf[2] + buf[3]);

        accl += ents / entj;
        __syncthreads();
    }
    if (tid == 0) out[0] = -0.5f * accl;
}

extern "C" void kernel_launch(void* const* d_in, const int* in_sizes, int n_in,
                              void* d_out, int out_size, void* d_ws, size_t ws_size,
                              hipStream_t stream) {
    const float* tar = (const float*)d_in[0];
    const float* src = (const float*)d_in[1];
    const int N = 2;
    const int P = in_sizes[0] / N;  // 884736

    float* pm = (float*)d_ws;
    unsigned* ctr = (unsigned*)((char*)d_ws + 4096);
    float* hist = (float*)((char*)d_ws + 8192);
    _Float16* bh = (_Float16*)((char*)d_ws + 40960);
    float* out = (float*)d_out;

    const size_t need = 40960 + (size_t)2 * GXN * HIST_ELEMS * sizeof(_Float16); // ~14.2 MB

    minmax_kernel<<<dim3(MMB, N, 2), 256, 0, stream>>>(tar, src, pm, ctr, hist, P);
    if (ws_size >= need) {
        scatter_hist_kernel<1><<<dim3(GXN, N), 256, 0, stream>>>(tar, src, pm, bh, hist, P);
        reduce_finalize_kernel<<<RED_BLOCKS, 256, 0, stream>>>(bh, hist, ctr, out, 1);
    } else {
        scatter_hist_kernel<0><<<dim3(GXN, N), 256, 0, stream>>>(tar, src, pm, bh, hist, P);
        reduce_finalize_kernel<<<RED_BLOCKS, 256, 0, stream>>>(bh, hist, ctr, out, 0);
    }
}

// Round 5
// 136.806 us; speedup vs baseline: 2.4374x; 2.3992x over previous
//
#include <hip/hip_runtime.h>
#include <math.h>

#define NBINS 64
#define HIST_ELEMS (NBINS*NBINS)
#define KBLKS 256               // K-blocks per (sample, col-half); grid 2*2*256 = 1024 = 4/CU
#define PTS_PER_BLOCK 3456      // 256 * 3456 = 884736 = P
#define CHUNKS 27               // per wave: 3456 / (4 waves * 32)
#define LSTRIDE 68              // col-major lh stride (b128 2-way banks = free)
// weight = exp2(-(u*SQK - b*SQK)^2); SQK = sqrt(8192/63^2*log2(e))
#define SQK 1.7256062f
#define MMB 128                 // minmax blocks per (n,t)
#define RED_BLOCKS 128
#define TILE_F16 2048           // 64 rows x 32 cols per bh tile

typedef float f4 __attribute__((ext_vector_type(4)));
typedef float f2 __attribute__((ext_vector_type(2)));
typedef float f32x4 __attribute__((ext_vector_type(4)));
typedef _Float16 half8 __attribute__((ext_vector_type(8)));
typedef int int4v __attribute__((ext_vector_type(4)));
typedef unsigned int u32x2 __attribute__((ext_vector_type(2)));

static __device__ __forceinline__ half8 pack8(const float* w) {
    int4v v;
    v[0] = __builtin_bit_cast(int, __builtin_amdgcn_cvt_pkrtz(w[0], w[1]));
    v[1] = __builtin_bit_cast(int, __builtin_amdgcn_cvt_pkrtz(w[2], w[3]));
    v[2] = __builtin_bit_cast(int, __builtin_amdgcn_cvt_pkrtz(w[4], w[5]));
    v[3] = __builtin_bit_cast(int, __builtin_amdgcn_cvt_pkrtz(w[6], w[7]));
    return __builtin_bit_cast(half8, v);
}

// packed-f32 math (gfx90a+): 2 f32 lanes per VALU issue
static __device__ __forceinline__ f2 pk_fma(f2 a, f2 b, f2 c) {
    f2 d;
    asm("v_pk_fma_f32 %0, %1, %2, %3" : "=v"(d) : "v"(a), "v"(b), "v"(c));
    return d;
}
static __device__ __forceinline__ f2 pk_mul(f2 a, f2 b) {
    f2 d;
    asm("v_pk_mul_f32 %0, %1, %2" : "=v"(d) : "v"(a), "v"(b));
    return d;
}

// ws layout: pm[1024] floats @0 | unsigned ctr @4096 | float hist[2][4096] @8192
//            | _Float16 bh[2*2*KBLKS][2048] @40960 (~4.2 MB)
__global__ __launch_bounds__(256) void minmax_kernel(const float* __restrict__ tar,
                                                     const float* __restrict__ src,
                                                     float* __restrict__ pm,
                                                     unsigned* __restrict__ ctr,
                                                     float* __restrict__ hist, int P) {
    const int b = blockIdx.x, n = blockIdx.y, t = blockIdx.z;
    const f4* x = (const f4*)((t == 0 ? tar : src) + (size_t)n * P);
    const int per = (P / 4) / MMB;   // 1728 f4 per block
    float lmin = INFINITY, lmax = -INFINITY;
    for (int i = b * per + threadIdx.x; i < (b + 1) * per; i += 256) {
        f4 v = x[i];
        lmin = fminf(lmin, fminf(fminf(v[0], v[1]), fminf(v[2], v[3])));
        lmax = fmaxf(lmax, fmaxf(fmaxf(v[0], v[1]), fmaxf(v[2], v[3])));
    }
    for (int off = 32; off > 0; off >>= 1) {
        lmin = fminf(lmin, __shfl_down(lmin, off, 64));
        lmax = fmaxf(lmax, __shfl_down(lmax, off, 64));
    }
    __shared__ float smin[4], smax[4];
    const int lane = threadIdx.x & 63, wave = threadIdx.x >> 6;
    if (lane == 0) { smin[wave] = lmin; smax[wave] = lmax; }
    __syncthreads();
    if (threadIdx.x == 0) {
        pm[(n * 2 + t) * MMB + b] =
            fminf(fminf(smin[0], smin[1]), fminf(smin[2], smin[3]));
        pm[512 + (n * 2 + t) * MMB + b] =
            fmaxf(fmaxf(smax[0], smax[1]), fmaxf(smax[2], smax[3]));
    }
    // zero global hist (8192 floats = 2048 f4 over 512 blocks = 4 f4 each) + counter
    const int flat = b + MMB * (n * 2 + t);   // 0..511
    f4* hz = (f4*)hist + flat * 4;
    const f4 z = {0.f, 0.f, 0.f, 0.f};
    if (threadIdx.x < 4) hz[threadIdx.x] = z;
    if (flat == 0 && threadIdx.x == 0) *ctr = 0u;
}

// Joint histogram as 64x64xP GEMM via MFMA f16 (round-1 structure), with the
// 64 s-bin output columns SPLIT across 2 blocks (h = bx>>8): acc 4x2 = 32
// regs instead of 64 -> unified VGPR+acc ~100 <= 128 -> 4 waves/SIMD HW tier
// (round 0/1 sat at 2 waves/SIMD: 84 arch VGPR + 64 acc = 148 > 128).
// A-side weights computed in both halves (1.5x exp2 total) -- the trade for
// 2x latency hiding.  LDS-atomic scatter is dead: rounds 3/4 proved LDS f32
// atomic RMW ~3.25 cyc/lane -> 233us floor for 25 adds/pair.
// A[m][k]: m=lane&15 (+16*mt), k=quad*8+j ; B[k][n]: n=lane&15, k=quad*8+j
// C/D: col=lane&15, row=quad*4+reg -> col-major lh; output TRANSPOSED
// (MI loss is transpose-invariant).
template <int STAGED>
__global__ __launch_bounds__(256, 4) void mfma_hist_kernel(const float* __restrict__ tar,
                                                           const float* __restrict__ src,
                                                           const float* __restrict__ pm,
                                                           _Float16* __restrict__ bh,
                                                           float* __restrict__ hist,
                                                           int P) {
    const int n = blockIdx.y;
    const int bx = blockIdx.x;
    const int kblk = bx & (KBLKS - 1);
    const int h = bx >> 8;               // s-bin column half: 0 or 1
    const int tid = threadIdx.x;
    const int lane = tid & 63, wave = tid >> 6;
    const int mlane = lane & 15, quad = lane >> 4;

    __shared__ float lh[32 * LSTRIDE];   // col-major: lh[col*LSTRIDE + row], 32 cols
    __shared__ float mmred[4];

    // --- wave 0: reduce the 128 per-block minmax partials ---
    if (wave == 0) {
        float a = fminf(pm[(n * 2 + 0) * MMB + lane], pm[(n * 2 + 0) * MMB + 64 + lane]);
        float b = fmaxf(pm[512 + (n * 2 + 0) * MMB + lane],
                        pm[512 + (n * 2 + 0) * MMB + 64 + lane]);
        float c = fminf(pm[(n * 2 + 1) * MMB + lane], pm[(n * 2 + 1) * MMB + 64 + lane]);
        float d = fmaxf(pm[512 + (n * 2 + 1) * MMB + lane],
                        pm[512 + (n * 2 + 1) * MMB + 64 + lane]);
        for (int off = 32; off > 0; off >>= 1) {
            a = fminf(a, __shfl_down(a, off, 64));
            b = fmaxf(b, __shfl_down(b, off, 64));
            c = fminf(c, __shfl_down(c, off, 64));
            d = fmaxf(d, __shfl_down(d, off, 64));
        }
        if (lane == 0) { mmred[0] = a; mmred[1] = b; mmred[2] = c; mmred[3] = d; }
    }
    __syncthreads();   // mmred ready

    const float tmin = mmred[0], tmax = mmred[1];
    const float smin = mmred[2], smax = mmred[3];
    const float tk = 63.0f / (tmax - tmin + 1e-10f) * SQK;
    const float sk = 63.0f / (smax - smin + 1e-10f) * SQK;
    const f2 tkk = {tk, tk}, skk = {sk, sk};
    f2 tneg[4], sneg[2];
    #pragma unroll
    for (int mt = 0; mt < 4; ++mt) {
        const float b = SQK * (float)(mlane + 16 * mt);
        const float tb_ = tmin * tk + b;
        tneg[mt] = {-tb_, -tb_};
    }
    #pragma unroll
    for (int nt = 0; nt < 2; ++nt) {
        const float b = SQK * (float)(mlane + 16 * nt + 32 * h);
        const float sb_ = smin * sk + b;
        sneg[nt] = {-sb_, -sb_};
    }

    f32x4 acc[4][2];
    #pragma unroll
    for (int a = 0; a < 4; ++a)
        #pragma unroll
        for (int b = 0; b < 2; ++b) acc[a][b] = (f32x4){0.f, 0.f, 0.f, 0.f};

    // --- compute: wave owns 864 points = 27 chunks of K=32, direct global ---
    const float* tg = tar + (size_t)n * P + (size_t)kblk * PTS_PER_BLOCK;
    const float* sg = src + (size_t)n * P + (size_t)kblk * PTS_PER_BLOCK;
    const int kwbase = wave * (32 * CHUNKS) + quad * 8;
    #pragma unroll 3
    for (int c = 0; c < CHUNKS; ++c) {
        const int kbase = kwbase + c * 32;
        const f4* pt4 = (const f4*)&tg[kbase];
        const f4* ps4 = (const f4*)&sg[kbase];
        f4 ta = pt4[0], tb = pt4[1];
        f4 sa = ps4[0], sb = ps4[1];
        f2 tp[4], sp[4];
        tp[0] = {ta[0], ta[1]}; tp[1] = {ta[2], ta[3]};
        tp[2] = {tb[0], tb[1]}; tp[3] = {tb[2], tb[3]};
        sp[0] = {sa[0], sa[1]}; sp[1] = {sa[2], sa[3]};
        sp[2] = {sb[0], sb[1]}; sp[3] = {sb[2], sb[3]};

        half8 af[4], bf[2];
        #pragma unroll
        for (int mt = 0; mt < 4; ++mt) {
            float w[8];
            #pragma unroll
            for (int hh = 0; hh < 4; ++hh) {
                f2 d = pk_fma(tp[hh], tkk, tneg[mt]);
                f2 s2 = pk_mul(d, d);
                w[2 * hh]     = __builtin_amdgcn_exp2f(-s2[0]);
                w[2 * hh + 1] = __builtin_amdgcn_exp2f(-s2[1]);
            }
            af[mt] = pack8(w);
        }
        #pragma unroll
        for (int nt = 0; nt < 2; ++nt) {
            float w[8];
            #pragma unroll
            for (int hh = 0; hh < 4; ++hh) {
                f2 d = pk_fma(sp[hh], skk, sneg[nt]);
                f2 s2 = pk_mul(d, d);
                w[2 * hh]     = __builtin_amdgcn_exp2f(-s2[0]);
                w[2 * hh + 1] = __builtin_amdgcn_exp2f(-s2[1]);
            }
            bf[nt] = pack8(w);
        }
        #pragma unroll
        for (int mt = 0; mt < 4; ++mt)
            #pragma unroll
            for (int nt = 0; nt < 2; ++nt)
                acc[mt][nt] = __builtin_amdgcn_mfma_f32_16x16x32_f16(
                    af[mt], bf[nt], acc[mt][nt], 0, 0, 0);
    }

    // --- serial-wave non-atomic combine into col-major lh (32 local cols) ---
    #pragma unroll
    for (int w = 0; w < 4; ++w) {
        if (wave == w) {
            #pragma unroll
            for (int nt = 0; nt < 2; ++nt)
                #pragma unroll
                for (int mt = 0; mt < 4; ++mt) {
                    f4* p = (f4*)&lh[(16 * nt + mlane) * LSTRIDE + 16 * mt + 4 * quad];
                    if (w == 0) {
                        *p = acc[mt][nt];
                    } else {
                        f4 v = *p;
                        v += acc[mt][nt];
                        *p = v;
                    }
                }
        }
        __syncthreads();
    }

    if (STAGED) {
        // pack col-major lh -> private 2048-entry f16 tile (col-major [c][r])
        const size_t tile = (size_t)((n * 2 + h) * KBLKS + kblk);
        u32x2* dst = (u32x2*)(bh + tile * TILE_F16);
        #pragma unroll
        for (int k = 0; k < 2; ++k) {
            const int i4 = tid + k * 256;          // 0..511, 4 f16 each
            const int c = i4 >> 4, r4 = (i4 & 15) * 4;
            f4 v = *(const f4*)&lh[c * LSTRIDE + r4];
            u32x2 o;
            o[0] = __builtin_bit_cast(unsigned int, __builtin_amdgcn_cvt_pkrtz(v[0], v[1]));
            o[1] = __builtin_bit_cast(unsigned int, __builtin_amdgcn_cvt_pkrtz(v[2], v[3]));
            dst[i4] = o;
        }
    } else {
        float* gh = hist + (size_t)n * HIST_ELEMS;
        for (int i = tid; i < TILE_F16; i += 256) {
            const int c = i >> 6, r = i & 63;
            unsafeAtomicAdd(&gh[(32 * h + c) * NBINS + r], lh[c * LSTRIDE + r]);
        }
    }
}

// 128 blocks: block b owns output column c = b&63 of sample n = b>>6.
// Threads: r = tid&63 (coalesced 128B f16 rows), seg = tid>>6 sums 64 of the
// 256 K-tiles; LDS combine; plain store hist[n][c][r].  Last block finalizes.
__global__ __launch_bounds__(256) void reduce_finalize_kernel(const _Float16* __restrict__ bh,
                                                              float* __restrict__ hist,
                                                              unsigned* __restrict__ ctr,
                                                              float* __restrict__ out,
                                                              int staged) {
    const int tid = threadIdx.x;
    const int lane = tid & 63, wave = tid >> 6;
    __shared__ float h2[2 * HIST_ELEMS];
    __shared__ float part[256];
    __shared__ float buf[4], rowsum[NBINS], colsum[NBINS], colp[4 * NBINS];
    __shared__ int lastflag;

    if (staged) {
        const int n = blockIdx.x >> 6;
        const int c = blockIdx.x & 63;
        const int h = c >> 5, cc = c & 31;
        const int r = tid & 63, seg = tid >> 6;
        const _Float16* p = bh +
            ((size_t)((n * 2 + h) * KBLKS + seg * 64)) * TILE_F16 + cc * 64 + r;
        float s = 0.0f;
        #pragma unroll 8
        for (int k = 0; k < 64; ++k) s += (float)p[(size_t)k * TILE_F16];
        part[tid] = s;
        __syncthreads();
        if (tid < 64)
            hist[(size_t)n * HIST_ELEMS + c * 64 + tid] =
                part[tid] + part[tid + 64] + part[tid + 128] + part[tid + 192];
    }

    __threadfence();
    if (tid == 0) {
        unsigned old = atomicAdd(ctr, 1u);
        lastflag = (old == RED_BLOCKS - 1) ? 1 : 0;
    }
    __syncthreads();
    if (!lastflag) return;

    // system-scope loads: bypass per-XCD L2 (writers fenced via threadfence)
    for (int i = tid; i < 2 * HIST_ELEMS; i += 256)
        h2[i] = __hip_atomic_load(&hist[i], __ATOMIC_RELAXED, __HIP_MEMORY_SCOPE_SYSTEM);
    __syncthreads();

    float accl = 0.0f;
    for (int nn = 0; nn < 2; ++nn) {
        const float* h = h2 + nn * HIST_ELEMS;
        {
            int r = tid >> 2, q = tid & 3;
            const float* hp = h + r * NBINS + q * 16;
            float sv = 0.0f;
            #pragma unroll
            for (int k = 0; k < 16; ++k) sv += hp[k];
            sv += __shfl_down(sv, 1, 64);
            sv += __shfl_down(sv, 2, 64);
            if (q == 0) rowsum[r] = sv;
        }
        {
            int c = tid & 63, g = tid >> 6;
            const float* hp = h + (g * 16) * NBINS + c;
            float sv = 0.0f;
            #pragma unroll
            for (int k = 0; k < 16; ++k) sv += hp[k * NBINS];
            colp[g * NBINS + c] = sv;
        }
        __syncthreads();
        if (tid < NBINS)
            colsum[tid] = colp[0 * NBINS + tid] + colp[1 * NBINS + tid] +
                          colp[2 * NBINS + tid] + colp[3 * NBINS + tid];
        __syncthreads();

        float tv = (tid < NBINS) ? rowsum[tid] : 0.0f;
        for (int off = 32; off > 0; off >>= 1) tv += __shfl_down(tv, off, 64);
        __syncthreads();
        if (lane == 0) buf[wave] = tv;
        __syncthreads();
        const float total = buf[0] + buf[1] + buf[2] + buf[3];
        const float inv = 1.0f / total;

        float ej = 0.0f;
        for (int i = tid; i < HIST_ELEMS; i += 256) {
            float p = h[i] * inv;
            ej += p * __logf(p + 1e-10f);
        }
        for (int off = 32; off > 0; off >>= 1) ej += __shfl_down(ej, off, 64);
        __syncthreads();
        if (lane == 0) buf[wave] = ej;
        __syncthreads();
        const float entj = -(buf[0] + buf[1] + buf[2] + buf[3]);

        float em = 0.0f;
        if (tid < NBINS) {
            float p = rowsum[tid] * inv;
            em = p * __logf(p + 1e-10f);
        } else if (tid < 2 * NBINS) {
            float p = colsum[tid - NBINS] * inv;
            em = p * __logf(p + 1e-10f);
        }
        for (int off = 32; off > 0; off >>= 1) em += __shfl_down(em, off, 64);
        __syncthreads();
        if (lane == 0) buf[wave] = em;
        __syncthreads();
        const float ents = -(buf[0] + buf[1] + buf[2] + buf[3]);

        accl += ents / entj;
        __syncthreads();
    }
    if (tid == 0) out[0] = -0.5f * accl;
}

extern "C" void kernel_launch(void* const* d_in, const int* in_sizes, int n_in,
                              void* d_out, int out_size, void* d_ws, size_t ws_size,
                              hipStream_t stream) {
    const float* tar = (const float*)d_in[0];
    const float* src = (const float*)d_in[1];
    const int N = 2;
    const int P = in_sizes[0] / N;  // 884736

    float* pm = (float*)d_ws;
    unsigned* ctr = (unsigned*)((char*)d_ws + 4096);
    float* hist = (float*)((char*)d_ws + 8192);
    _Float16* bh = (_Float16*)((char*)d_ws + 40960);
    float* out = (float*)d_out;

    const size_t need = 40960 + (size_t)2 * 2 * KBLKS * TILE_F16 * sizeof(_Float16); // ~4.2 MB

    minmax_kernel<<<dim3(MMB, N, 2), 256, 0, stream>>>(tar, src, pm, ctr, hist, P);
    if (ws_size >= need) {
        mfma_hist_kernel<1><<<dim3(2 * KBLKS, N), 256, 0, stream>>>(tar, src, pm, bh, hist, P);
        reduce_finalize_kernel<<<RED_BLOCKS, 256, 0, stream>>>(bh, hist, ctr, out, 1);
    } else {
        mfma_hist_kernel<0><<<dim3(2 * KBLKS, N), 256, 0, stream>>>(tar, src, pm, bh, hist, P);
        reduce_finalize_kernel<<<RED_BLOCKS, 256, 0, stream>>>(bh, hist, ctr, out, 0);
    }
}

// Round 7
// 135.549 us; speedup vs baseline: 2.4600x; 1.0093x over previous
//
#include <hip/hip_runtime.h>
#include <math.h>

#define NBINS 64
#define HIST_ELEMS (NBINS*NBINS)
#define PTS_PER_BLOCK 2304      // 384 blocks/n * 2304 = 884736 = P; grid 768 = 3/CU even
#define GXN 384                 // hist blocks per sample
#define CHUNKS 18               // per wave: 2304 / (4 waves * 32)
#define LSTRIDE 68              // col-major lh stride (b128 2-way banks = free)
// weight = exp2(-(u*SQK - b*SQK)^2); SQK = sqrt(8192/63^2*log2(e))
#define SQK 1.7256062f
#define RED_BLOCKS 128
#define TILES_PER_WAVE (GXN/4)  // 96

typedef float f4 __attribute__((ext_vector_type(4)));
typedef float f2 __attribute__((ext_vector_type(2)));
typedef float f32x4 __attribute__((ext_vector_type(4)));
typedef _Float16 half8 __attribute__((ext_vector_type(8)));
typedef int int4v __attribute__((ext_vector_type(4)));
typedef unsigned int u32x2 __attribute__((ext_vector_type(2)));

static __device__ __forceinline__ half8 pack8(const float* w) {
    int4v v;
    v[0] = __builtin_bit_cast(int, __builtin_amdgcn_cvt_pkrtz(w[0], w[1]));
    v[1] = __builtin_bit_cast(int, __builtin_amdgcn_cvt_pkrtz(w[2], w[3]));
    v[2] = __builtin_bit_cast(int, __builtin_amdgcn_cvt_pkrtz(w[4], w[5]));
    v[3] = __builtin_bit_cast(int, __builtin_amdgcn_cvt_pkrtz(w[6], w[7]));
    return __builtin_bit_cast(half8, v);
}

// packed-f32 math (gfx90a+): 2 f32 lanes per VALU issue
static __device__ __forceinline__ f2 pk_fma(f2 a, f2 b, f2 c) {
    f2 d;
    asm("v_pk_fma_f32 %0, %1, %2, %3" : "=v"(d) : "v"(a), "v"(b), "v"(c));
    return d;
}
static __device__ __forceinline__ f2 pk_mul(f2 a, f2 b) {
    f2 d;
    asm("v_pk_mul_f32 %0, %1, %2" : "=v"(d) : "v"(a), "v"(b));
    return d;
}

// ws layout: pm[512] floats @0 | unsigned ctr @2048 | float hist[2][4096] @4096
//            | _Float16 bh[2*GXN][4096] @36864
__global__ __launch_bounds__(256) void minmax_kernel(const float* __restrict__ tar,
                                                     const float* __restrict__ src,
                                                     float* __restrict__ pm,
                                                     unsigned* __restrict__ ctr,
                                                     float* __restrict__ hist, int P) {
    const int b = blockIdx.x, n = blockIdx.y, t = blockIdx.z;
    const f4* x = (const f4*)((t == 0 ? tar : src) + (size_t)n * P);
    const int per = (P / 4) / 64;   // 3456 f4 per block
    float lmin = INFINITY, lmax = -INFINITY;
    for (int i = b * per + threadIdx.x; i < (b + 1) * per; i += 256) {
        f4 v = x[i];
        lmin = fminf(lmin, fminf(fminf(v[0], v[1]), fminf(v[2], v[3])));
        lmax = fmaxf(lmax, fmaxf(fmaxf(v[0], v[1]), fmaxf(v[2], v[3])));
    }
    for (int off = 32; off > 0; off >>= 1) {
        lmin = fminf(lmin, __shfl_down(lmin, off, 64));
        lmax = fmaxf(lmax, __shfl_down(lmax, off, 64));
    }
    __shared__ float smin[4], smax[4];
    const int lane = threadIdx.x & 63, wave = threadIdx.x >> 6;
    if (lane == 0) { smin[wave] = lmin; smax[wave] = lmax; }
    __syncthreads();
    if (threadIdx.x == 0) {
        pm[(n * 2 + t) * 64 + b] =
            fminf(fminf(smin[0], smin[1]), fminf(smin[2], smin[3]));
        pm[256 + (n * 2 + t) * 64 + b] =
            fmaxf(fmaxf(smax[0], smax[1]), fmaxf(smax[2], smax[3]));
    }
    // zero global hist (8192 floats over 256 blocks = 8 f4 each) + counter
    const int flat = b + 64 * n + 128 * t;   // 0..255
    f4* hz = (f4*)hist + flat * 8;
    const f4 z = {0.f, 0.f, 0.f, 0.f};
    if (threadIdx.x < 8) hz[threadIdx.x] = z;
    if (flat == 0 && threadIdx.x == 0) *ctr = 0u;
}

// Joint histogram as 64x64xP GEMM via MFMA f16 -- round-1 structure (the
// 129.2us/40.8us champion), with LDS INPUT STAGING REMOVED: each wave reads
// only its own contiguous 576-float range; 16 lanes of a quad-row broadcast
// the same 32B (dedup'd in L1) -- round-5 proved this addressing correct and
// FETCH-neutral.  LDS = lh only (17.9 KB).  Weight math/combine/pack are
// byte-identical to round 1 (the round-6 recurrence NaN'd -> rebased).
// Ledger: LDS-atomic scatter dead (r3/4: ~3.25cyc/lane RMW), column-split
// dead (r5: 1.5x A-weights), launch_bounds cap dead (r2: acc spill).
// A[m][k]: m=lane&15 (+16*mt), k=quad*8+j ; B[k][n]: n=lane&15, k=quad*8+j
// C/D: col=lane&15, row=quad*4+reg -> col-major lh; output TRANSPOSED
// (MI loss is transpose-invariant).
template <int STAGED>
__global__ __launch_bounds__(256) void mfma_hist_kernel(const float* __restrict__ tar,
                                                        const float* __restrict__ src,
                                                        const float* __restrict__ pm,
                                                        _Float16* __restrict__ bh,
                                                        float* __restrict__ hist,
                                                        int P) {
    const int n = blockIdx.y;
    const int bx = blockIdx.x;
    const int tid = threadIdx.x;
    const int lane = tid & 63, wave = tid >> 6;
    const int mlane = lane & 15, quad = lane >> 4;

    __shared__ float lh[NBINS * LSTRIDE];   // col-major: lh[col*LSTRIDE + row]
    __shared__ float mmred[4];

    // --- wave 0: reduce the 64 per-block minmax partials ---
    if (wave == 0) {
        float a = pm[(n * 2 + 0) * 64 + lane];
        float b = pm[256 + (n * 2 + 0) * 64 + lane];
        float c = pm[(n * 2 + 1) * 64 + lane];
        float d = pm[256 + (n * 2 + 1) * 64 + lane];
        for (int off = 32; off > 0; off >>= 1) {
            a = fminf(a, __shfl_down(a, off, 64));
            b = fmaxf(b, __shfl_down(b, off, 64));
            c = fminf(c, __shfl_down(c, off, 64));
            d = fmaxf(d, __shfl_down(d, off, 64));
        }
        if (lane == 0) { mmred[0] = a; mmred[1] = b; mmred[2] = c; mmred[3] = d; }
    }
    __syncthreads();   // mmred ready

    const float tmin = mmred[0], tmax = mmred[1];
    const float smin = mmred[2], smax = mmred[3];
    const float tk = 63.0f / (tmax - tmin + 1e-10f) * SQK;
    const float sk = 63.0f / (smax - smin + 1e-10f) * SQK;
    const f2 tkk = {tk, tk}, skk = {sk, sk};
    f2 tneg[4], sneg[4];
    #pragma unroll
    for (int mt = 0; mt < 4; ++mt) {
        const float b = SQK * (float)(mlane + 16 * mt);
        const float tb_ = tmin * tk + b;
        const float sb_ = smin * sk + b;
        tneg[mt] = {-tb_, -tb_};
        sneg[mt] = {-sb_, -sb_};
    }

    f32x4 acc[4][4];
    #pragma unroll
    for (int a = 0; a < 4; ++a)
        #pragma unroll
        for (int b = 0; b < 4; ++b) acc[a][b] = (f32x4){0.f, 0.f, 0.f, 0.f};

    // --- compute: wave owns 576 points = 18 chunks of K=32, direct global ---
    const f4* tg4 = (const f4*)(tar + (size_t)n * P + (size_t)bx * PTS_PER_BLOCK);
    const f4* sg4 = (const f4*)(src + (size_t)n * P + (size_t)bx * PTS_PER_BLOCK);
    const int kw4 = wave * 144 + quad * 2;      // f4 index of this lane's first pair
    #pragma unroll 3
    for (int c = 0; c < CHUNKS; ++c) {
        const int i4 = kw4 + c * 8;
        f4 ta = tg4[i4], tb = tg4[i4 + 1];
        f4 sa = sg4[i4], sb = sg4[i4 + 1];
        f2 tp[4], sp[4];
        tp[0] = {ta[0], ta[1]}; tp[1] = {ta[2], ta[3]};
        tp[2] = {tb[0], tb[1]}; tp[3] = {tb[2], tb[3]};
        sp[0] = {sa[0], sa[1]}; sp[1] = {sa[2], sa[3]};
        sp[2] = {sb[0], sb[1]}; sp[3] = {sb[2], sb[3]};

        half8 af[4], bf[4];
        #pragma unroll
        for (int mt = 0; mt < 4; ++mt) {
            float w[8];
            #pragma unroll
            for (int h = 0; h < 4; ++h) {
                f2 d = pk_fma(tp[h], tkk, tneg[mt]);
                f2 s2 = pk_mul(d, d);
                w[2 * h]     = __builtin_amdgcn_exp2f(-s2[0]);
                w[2 * h + 1] = __builtin_amdgcn_exp2f(-s2[1]);
            }
            af[mt] = pack8(w);
        }
        #pragma unroll
        for (int nt = 0; nt < 4; ++nt) {
            float w[8];
            #pragma unroll
            for (int h = 0; h < 4; ++h) {
                f2 d = pk_fma(sp[h], skk, sneg[nt]);
                f2 s2 = pk_mul(d, d);
                w[2 * h]     = __builtin_amdgcn_exp2f(-s2[0]);
                w[2 * h + 1] = __builtin_amdgcn_exp2f(-s2[1]);
            }
            bf[nt] = pack8(w);
        }
        #pragma unroll
        for (int mt = 0; mt < 4; ++mt)
            #pragma unroll
            for (int nt = 0; nt < 4; ++nt)
                acc[mt][nt] = __builtin_amdgcn_mfma_f32_16x16x32_f16(
                    af[mt], bf[nt], acc[mt][nt], 0, 0, 0);
    }

    // --- serial-wave non-atomic combine into col-major lh ---
    #pragma unroll
    for (int w = 0; w < 4; ++w) {
        if (wave == w) {
            #pragma unroll
            for (int nt = 0; nt < 4; ++nt)
                #pragma unroll
                for (int mt = 0; mt < 4; ++mt) {
                    f4* p = (f4*)&lh[(16 * nt + mlane) * LSTRIDE + 16 * mt + 4 * quad];
                    if (w == 0) {
                        *p = acc[mt][nt];
                    } else {
                        f4 v = *p;
                        v += acc[mt][nt];
                        *p = v;
                    }
                }
        }
        __syncthreads();
    }

    if (STAGED) {
        // compact col-major lh -> private dense 4096-entry f16 tile (no atomics)
        u32x2* dst = (u32x2*)(bh + ((size_t)n * GXN + bx) * HIST_ELEMS);
        #pragma unroll
        for (int k = 0; k < 4; ++k) {
            const int i4 = tid + k * 256;          // 0..1023, 4 f16 each
            const int c = i4 >> 4, r4 = (i4 & 15) * 4;
            f4 v = *(const f4*)&lh[c * LSTRIDE + r4];
            u32x2 o;
            o[0] = __builtin_bit_cast(unsigned int, __builtin_amdgcn_cvt_pkrtz(v[0], v[1]));
            o[1] = __builtin_bit_cast(unsigned int, __builtin_amdgcn_cvt_pkrtz(v[2], v[3]));
            dst[i4] = o;
        }
    } else {
        float* gh = hist + (size_t)n * HIST_ELEMS;
        for (int i = tid; i < HIST_ELEMS; i += 256) {
            const int c = i >> 6, r = i & 63;
            unsafeAtomicAdd(&gh[i], lh[c * LSTRIDE + r]);
        }
    }
}

// 128 blocks: each owns 64 hist elements; each wave sums 96 f16 tiles,
// LDS-combine, plain store -> hist.  Last-arriving block finalizes.
__global__ __launch_bounds__(256) void reduce_finalize_kernel(const _Float16* __restrict__ bh,
                                                              float* __restrict__ hist,
                                                              unsigned* __restrict__ ctr,
                                                              float* __restrict__ out,
                                                              int staged) {
    const int tid = threadIdx.x;
    const int lane = tid & 63, wave = tid >> 6;
    __shared__ float h2[2 * HIST_ELEMS];
    __shared__ float buf[4], rowsum[NBINS], colsum[NBINS], colp[4 * NBINS];
    __shared__ float part[4][64];
    __shared__ int lastflag;

    if (staged) {
        const int g = blockIdx.x * 64 + lane;   // 0..8191
        const int n = g >> 12, e = g & 4095;
        const _Float16* p = bh + (((size_t)(n * GXN + wave * TILES_PER_WAVE)) << 12) + e;
        float s = 0.0f;
        #pragma unroll 8
        for (int b = 0; b < TILES_PER_WAVE; ++b) s += (float)p[(size_t)b << 12];
        part[wave][lane] = s;
        __syncthreads();
        if (wave == 0)
            hist[g] = part[0][lane] + part[1][lane] + part[2][lane] + part[3][lane];
    }

    __threadfence();
    if (tid == 0) {
        unsigned old = atomicAdd(ctr, 1u);
        lastflag = (old == RED_BLOCKS - 1) ? 1 : 0;
    }
    __syncthreads();
    if (!lastflag) return;

    // system-scope loads: bypass per-XCD L2 (writers fenced via threadfence)
    for (int i = tid; i < 2 * HIST_ELEMS; i += 256)
        h2[i] = __hip_atomic_load(&hist[i], __ATOMIC_RELAXED, __HIP_MEMORY_SCOPE_SYSTEM);
    __syncthreads();

    float accl = 0.0f;
    for (int nn = 0; nn < 2; ++nn) {
        const float* h = h2 + nn * HIST_ELEMS;
        {
            int r = tid >> 2, q = tid & 3;
            const float* hp = h + r * NBINS + q * 16;
            float sv = 0.0f;
            #pragma unroll
            for (int k = 0; k < 16; ++k) sv += hp[k];
            sv += __shfl_down(sv, 1, 64);
            sv += __shfl_down(sv, 2, 64);
            if (q == 0) rowsum[r] = sv;
        }
        {
            int c = tid & 63, g = tid >> 6;
            const float* hp = h + (g * 16) * NBINS + c;
            float sv = 0.0f;
            #pragma unroll
            for (int k = 0; k < 16; ++k) sv += hp[k * NBINS];
            colp[g * NBINS + c] = sv;
        }
        __syncthreads();
        if (tid < NBINS)
            colsum[tid] = colp[0 * NBINS + tid] + colp[1 * NBINS + tid] +
                          colp[2 * NBINS + tid] + colp[3 * NBINS + tid];
        __syncthreads();

        float tv = (tid < NBINS) ? rowsum[tid] : 0.0f;
        for (int off = 32; off > 0; off >>= 1) tv += __shfl_down(tv, off, 64);
        __syncthreads();
        if (lane == 0) buf[wave] = tv;
        __syncthreads();
        const float total = buf[0] + buf[1] + buf[2] + buf[3];
        const float inv = 1.0f / total;

        float ej = 0.0f;
        for (int i = tid; i < HIST_ELEMS; i += 256) {
            float p = h[i] * inv;
            ej += p * __logf(p + 1e-10f);
        }
        for (int off = 32; off > 0; off >>= 1) ej += __shfl_down(ej, off, 64);
        __syncthreads();
        if (lane == 0) buf[wave] = ej;
        __syncthreads();
        const float entj = -(buf[0] + buf[1] + buf[2] + buf[3]);

        float em = 0.0f;
        if (tid < NBINS) {
            float p = rowsum[tid] * inv;
            em = p * __logf(p + 1e-10f);
        } else if (tid < 2 * NBINS) {
            float p = colsum[tid - NBINS] * inv;
            em = p * __logf(p + 1e-10f);
        }
        for (int off = 32; off > 0; off >>= 1) em += __shfl_down(em, off, 64);
        __syncthreads();
        if (lane == 0) buf[wave] = em;
        __syncthreads();
        const float ents = -(buf[0] + buf[1] + buf[2] + buf[3]);

        accl += ents / entj;
        __syncthreads();
    }
    if (tid == 0) out[0] = -0.5f * accl;
}

extern "C" void kernel_launch(void* const* d_in, const int* in_sizes, int n_in,
                              void* d_out, int out_size, void* d_ws, size_t ws_size,
                              hipStream_t stream) {
    const float* tar = (const float*)d_in[0];
    const float* src = (const float*)d_in[1];
    const int N = 2;
    const int P = in_sizes[0] / N;  // 884736

    float* pm = (float*)d_ws;
    unsigned* ctr = (unsigned*)((char*)d_ws + 2048);
    float* hist = (float*)((char*)d_ws + 4096);
    _Float16* bh = (_Float16*)((char*)d_ws + 36864);
    float* out = (float*)d_out;

    const size_t need = 36864 + (size_t)2 * GXN * HIST_ELEMS * sizeof(_Float16); // ~6.33 MB

    minmax_kernel<<<dim3(64, N, 2), 256, 0, stream>>>(tar, src, pm, ctr, hist, P);
    if (ws_size >= need) {
        mfma_hist_kernel<1><<<dim3(GXN, N), 256, 0, stream>>>(tar, src, pm, bh, hist, P);
        reduce_finalize_kernel<<<RED_BLOCKS, 256, 0, stream>>>(bh, hist, ctr, out, 1);
    } else {
        mfma_hist_kernel<0><<<dim3(GXN, N), 256, 0, stream>>>(tar, src, pm, bh, hist, P);
        reduce_finalize_kernel<<<RED_BLOCKS, 256, 0, stream>>>(bh, hist, ctr, out, 0);
    }
}

// Round 8
// 132.194 us; speedup vs baseline: 2.5224x; 1.0254x over previous
//
#include <hip/hip_runtime.h>
#include <math.h>

#define NBINS 64
#define HIST_ELEMS (NBINS*NBINS)
#define PTS_PER_BLOCK 1728      // 512 blocks/n * 1728 = 884736 = P; grid 1024 = 4/CU even
#define GXN 512                 // hist blocks per sample
#define LSTRIDE 68              // col-major lh stride (b128 2-way banks = free)
// weight = exp2(-(u*SQK - b*SQK)^2); SQK = sqrt(8192/63^2*log2(e))
#define SQK 1.7256062f
#define RED_BLOCKS 128
#define TILES_PER_WAVE (GXN/4)  // 128
#define SMEM_FLOATS (2*PTS_PER_BLOCK + NBINS*LSTRIDE)   // 7808 floats = 31232 B

typedef float f4 __attribute__((ext_vector_type(4)));
typedef float f2 __attribute__((ext_vector_type(2)));
typedef float f32x4 __attribute__((ext_vector_type(4)));
typedef _Float16 half8 __attribute__((ext_vector_type(8)));
typedef int int4v __attribute__((ext_vector_type(4)));
typedef unsigned int u32x2 __attribute__((ext_vector_type(2)));

static __device__ __forceinline__ half8 pack8(const float* w) {
    int4v v;
    v[0] = __builtin_bit_cast(int, __builtin_amdgcn_cvt_pkrtz(w[0], w[1]));
    v[1] = __builtin_bit_cast(int, __builtin_amdgcn_cvt_pkrtz(w[2], w[3]));
    v[2] = __builtin_bit_cast(int, __builtin_amdgcn_cvt_pkrtz(w[4], w[5]));
    v[3] = __builtin_bit_cast(int, __builtin_amdgcn_cvt_pkrtz(w[6], w[7]));
    return __builtin_bit_cast(half8, v);
}

// packed-f32 math (gfx90a+): 2 f32 lanes per VALU issue
static __device__ __forceinline__ f2 pk_fma(f2 a, f2 b, f2 c) {
    f2 d;
    asm("v_pk_fma_f32 %0, %1, %2, %3" : "=v"(d) : "v"(a), "v"(b), "v"(c));
    return d;
}
static __device__ __forceinline__ f2 pk_mul(f2 a, f2 b) {
    f2 d;
    asm("v_pk_mul_f32 %0, %1, %2" : "=v"(d) : "v"(a), "v"(b));
    return d;
}
static __device__ __forceinline__ f2 pk_add(f2 a, f2 b) {
    f2 d;
    asm("v_pk_add_f32 %0, %1, %2" : "=v"(d) : "v"(a), "v"(b));
    return d;
}

// ws layout: pm[512] floats @0 | unsigned ctr @2048 | float hist[2][4096] @4096
//            | _Float16 bh[2*GXN][4096] @36864 (~8.4 MB)
__global__ __launch_bounds__(256) void minmax_kernel(const float* __restrict__ tar,
                                                     const float* __restrict__ src,
                                                     float* __restrict__ pm,
                                                     unsigned* __restrict__ ctr,
                                                     float* __restrict__ hist, int P) {
    const int b = blockIdx.x, n = blockIdx.y, t = blockIdx.z;
    const f4* x = (const f4*)((t == 0 ? tar : src) + (size_t)n * P);
    const int per = (P / 4) / 64;   // 3456 f4 per block
    float lmin = INFINITY, lmax = -INFINITY;
    for (int i = b * per + threadIdx.x; i < (b + 1) * per; i += 256) {
        f4 v = x[i];
        lmin = fminf(lmin, fminf(fminf(v[0], v[1]), fminf(v[2], v[3])));
        lmax = fmaxf(lmax, fmaxf(fmaxf(v[0], v[1]), fmaxf(v[2], v[3])));
    }
    for (int off = 32; off > 0; off >>= 1) {
        lmin = fminf(lmin, __shfl_down(lmin, off, 64));
        lmax = fmaxf(lmax, __shfl_down(lmax, off, 64));
    }
    __shared__ float smin[4], smax[4];
    const int lane = threadIdx.x & 63, wave = threadIdx.x >> 6;
    if (lane == 0) { smin[wave] = lmin; smax[wave] = lmax; }
    __syncthreads();
    if (threadIdx.x == 0) {
        pm[(n * 2 + t) * 64 + b] =
            fminf(fminf(smin[0], smin[1]), fminf(smin[2], smin[3]));
        pm[256 + (n * 2 + t) * 64 + b] =
            fmaxf(fmaxf(smax[0], smax[1]), fmaxf(smax[2], smax[3]));
    }
    // zero global hist (8192 floats over 256 blocks = 8 f4 each) + counter
    const int flat = b + 64 * n + 128 * t;   // 0..255
    f4* hz = (f4*)hist + flat * 8;
    const f4 z = {0.f, 0.f, 0.f, 0.f};
    if (threadIdx.x < 8) hz[threadIdx.x] = z;
    if (flat == 0 && threadIdx.x == 0) *ctr = 0u;
}

// Joint histogram as 64x64xP GEMM via MFMA f16 -- the r1 champion structure
// (LDS staging, serial-wave combine, f16 bh tiles), restructured for the
// 4-waves/SIMD register tier (unified VGPR+acc <= 128):
//   * bf[0..3] computed first; af STREAMED one tile at a time (saves 12 regs)
//   * tneg/sneg[4] replaced by base + 3 broadcast consts (-16*SQK*mt): per
//     pair e = pk_fma(x,k,base) hoisted, per tile d = pk_add(e, cm) (saves 12)
//   * __launch_bounds__(256,4): cap 128 vs ~124 demand (r2's trap was 85 vs 148)
//   * grid GXN=512 -> 1024 blocks = exactly 4/CU; waves take 14/14/13/13
//     chunks of K=32 (1728 pts/block), skew absorbed at the combine barrier.
// Ledger: scatter dead (r3/4: ~3.25cyc/lane LDS RMW), col-split dead (r5),
// recurrence NaN (r6), unstaged dead (r7: 56us), forced occ w/o reg cut (r2).
// A[m][k]: m=lane&15 (+16*mt), k=quad*8+j ; B[k][n]: n=lane&15, k=quad*8+j
// C/D: col=lane&15, row=quad*4+reg -> col-major lh; output TRANSPOSED
// (MI loss is transpose-invariant).
template <int STAGED>
__global__ __launch_bounds__(256, 4) void mfma_hist_kernel(const float* __restrict__ tar,
                                                           const float* __restrict__ src,
                                                           const float* __restrict__ pm,
                                                           _Float16* __restrict__ bh,
                                                           float* __restrict__ hist,
                                                           int P) {
    const int n = blockIdx.y;
    const int bx = blockIdx.x;
    const int tid = threadIdx.x;
    const int lane = tid & 63, wave = tid >> 6;
    const int mlane = lane & 15, quad = lane >> 4;

    __shared__ float smem[SMEM_FLOATS];
    __shared__ float mmred[4];
    float* su_t = smem;
    float* su_s = smem + PTS_PER_BLOCK;
    float* lh = smem + 2 * PTS_PER_BLOCK;   // col-major: lh[col*LSTRIDE + row]

    // --- wave 0: reduce the 64 per-block minmax partials ---
    if (wave == 0) {
        float a = pm[(n * 2 + 0) * 64 + lane];
        float b = pm[256 + (n * 2 + 0) * 64 + lane];
        float c = pm[(n * 2 + 1) * 64 + lane];
        float d = pm[256 + (n * 2 + 1) * 64 + lane];
        for (int off = 32; off > 0; off >>= 1) {
            a = fminf(a, __shfl_down(a, off, 64));
            b = fmaxf(b, __shfl_down(b, off, 64));
            c = fminf(c, __shfl_down(c, off, 64));
            d = fmaxf(d, __shfl_down(d, off, 64));
        }
        if (lane == 0) { mmred[0] = a; mmred[1] = b; mmred[2] = c; mmred[3] = d; }
    }

    // --- stage raw inputs: 432 f4 per tensor, coalesced ---
    {
        const f4* tg = (const f4*)(tar + (size_t)n * P + (size_t)bx * PTS_PER_BLOCK);
        const f4* sg = (const f4*)(src + (size_t)n * P + (size_t)bx * PTS_PER_BLOCK);
        f4* st4 = (f4*)su_t;
        f4* ss4 = (f4*)su_s;
        {
            const int i = tid;
            st4[i] = tg[i];
            ss4[i] = sg[i];
        }
        if (tid < 176) {
            const int i = 256 + tid;
            st4[i] = tg[i];
            ss4[i] = sg[i];
        }
    }
    __syncthreads();   // staging + mmred complete

    const float tmin = mmred[0], tmax = mmred[1];
    const float smin = mmred[2], smax = mmred[3];
    const float tk = 63.0f / (tmax - tmin + 1e-10f) * SQK;
    const float sk = 63.0f / (smax - smin + 1e-10f) * SQK;
    const f2 tkk = {tk, tk}, skk = {sk, sk};
    const float tb0 = -(tmin * tk + SQK * (float)mlane);
    const float sb0 = -(smin * sk + SQK * (float)mlane);
    const f2 tbase = {tb0, tb0};
    const f2 sbase = {sb0, sb0};
    f2 cmv[3];
    #pragma unroll
    for (int m = 0; m < 3; ++m) {
        const float c = -16.0f * SQK * (float)(m + 1);
        cmv[m] = {c, c};
    }

    f32x4 acc[4][4];
    #pragma unroll
    for (int a = 0; a < 4; ++a)
        #pragma unroll
        for (int b = 0; b < 4; ++b) acc[a][b] = (f32x4){0.f, 0.f, 0.f, 0.f};

    // --- compute: waves own 448/448/416/416 points (14/14/13/13 chunks) ---
    const int wb = (wave < 2) ? wave * 448 : 896 + (wave - 2) * 416;
    const int nc = (wave < 2) ? 14 : 13;
    #pragma unroll 1
    for (int c = 0; c < nc; ++c) {
        const int kbase = wb + c * 32 + quad * 8;
        const f4* pt4 = (const f4*)&su_t[kbase];
        const f4* ps4 = (const f4*)&su_s[kbase];
        f4 ta = pt4[0], tb = pt4[1];
        f4 sa = ps4[0], sb = ps4[1];
        f2 et[4], es[4];
        et[0] = pk_fma((f2){ta[0], ta[1]}, tkk, tbase);
        et[1] = pk_fma((f2){ta[2], ta[3]}, tkk, tbase);
        et[2] = pk_fma((f2){tb[0], tb[1]}, tkk, tbase);
        et[3] = pk_fma((f2){tb[2], tb[3]}, tkk, tbase);
        es[0] = pk_fma((f2){sa[0], sa[1]}, skk, sbase);
        es[1] = pk_fma((f2){sa[2], sa[3]}, skk, sbase);
        es[2] = pk_fma((f2){sb[0], sb[1]}, skk, sbase);
        es[3] = pk_fma((f2){sb[2], sb[3]}, skk, sbase);

        half8 bf[4];
        #pragma unroll
        for (int nt = 0; nt < 4; ++nt) {
            float w[8];
            #pragma unroll
            for (int h = 0; h < 4; ++h) {
                f2 d = (nt == 0) ? es[h] : pk_add(es[h], cmv[nt - 1]);
                f2 s2 = pk_mul(d, d);
                w[2 * h]     = __builtin_amdgcn_exp2f(-s2[0]);
                w[2 * h + 1] = __builtin_amdgcn_exp2f(-s2[1]);
            }
            bf[nt] = pack8(w);
        }
        #pragma unroll
        for (int mt = 0; mt < 4; ++mt) {
            float w[8];
            #pragma unroll
            for (int h = 0; h < 4; ++h) {
                f2 d = (mt == 0) ? et[h] : pk_add(et[h], cmv[mt - 1]);
                f2 s2 = pk_mul(d, d);
                w[2 * h]     = __builtin_amdgcn_exp2f(-s2[0]);
                w[2 * h + 1] = __builtin_amdgcn_exp2f(-s2[1]);
            }
            half8 af = pack8(w);
            #pragma unroll
            for (int nt = 0; nt < 4; ++nt)
                acc[mt][nt] = __builtin_amdgcn_mfma_f32_16x16x32_f16(
                    af, bf[nt], acc[mt][nt], 0, 0, 0);
        }
    }

    // --- serial-wave non-atomic combine into col-major lh ---
    #pragma unroll
    for (int w = 0; w < 4; ++w) {
        if (wave == w) {
            #pragma unroll
            for (int nt = 0; nt < 4; ++nt)
                #pragma unroll
                for (int mt = 0; mt < 4; ++mt) {
                    f4* p = (f4*)&lh[(16 * nt + mlane) * LSTRIDE + 16 * mt + 4 * quad];
                    if (w == 0) {
                        *p = acc[mt][nt];
                    } else {
                        f4 v = *p;
                        v += acc[mt][nt];
                        *p = v;
                    }
                }
        }
        __syncthreads();
    }

    if (STAGED) {
        // compact col-major lh -> private dense 4096-entry f16 tile (no atomics)
        u32x2* dst = (u32x2*)(bh + ((size_t)n * GXN + bx) * HIST_ELEMS);
        #pragma unroll
        for (int k = 0; k < 4; ++k) {
            const int i4 = tid + k * 256;          // 0..1023, 4 f16 each
            const int c = i4 >> 4, r4 = (i4 & 15) * 4;
            f4 v = *(const f4*)&lh[c * LSTRIDE + r4];
            u32x2 o;
            o[0] = __builtin_bit_cast(unsigned int, __builtin_amdgcn_cvt_pkrtz(v[0], v[1]));
            o[1] = __builtin_bit_cast(unsigned int, __builtin_amdgcn_cvt_pkrtz(v[2], v[3]));
            dst[i4] = o;
        }
    } else {
        float* gh = hist + (size_t)n * HIST_ELEMS;
        for (int i = tid; i < HIST_ELEMS; i += 256) {
            const int c = i >> 6, r = i & 63;
            unsafeAtomicAdd(&gh[i], lh[c * LSTRIDE + r]);
        }
    }
}

// 128 blocks: each owns 64 hist elements; each wave sums 128 f16 tiles,
// LDS-combine, plain store -> hist.  Last-arriving block finalizes.
__global__ __launch_bounds__(256) void reduce_finalize_kernel(const _Float16* __restrict__ bh,
                                                              float* __restrict__ hist,
                                                              unsigned* __restrict__ ctr,
                                                              float* __restrict__ out,
                                                              int staged) {
    const int tid = threadIdx.x;
    const int lane = tid & 63, wave = tid >> 6;
    __shared__ float h2[2 * HIST_ELEMS];
    __shared__ float buf[4], rowsum[NBINS], colsum[NBINS], colp[4 * NBINS];
    __shared__ float part[4][64];
    __shared__ int lastflag;

    if (staged) {
        const int g = blockIdx.x * 64 + lane;   // 0..8191
        const int n = g >> 12, e = g & 4095;
        const _Float16* p = bh + (((size_t)(n * GXN + wave * TILES_PER_WAVE)) << 12) + e;
        float s = 0.0f;
        #pragma unroll 8
        for (int b = 0; b < TILES_PER_WAVE; ++b) s += (float)p[(size_t)b << 12];
        part[wave][lane] = s;
        __syncthreads();
        if (wave == 0)
            hist[g] = part[0][lane] + part[1][lane] + part[2][lane] + part[3][lane];
    }

    __threadfence();
    if (tid == 0) {
        unsigned old = atomicAdd(ctr, 1u);
        lastflag = (old == RED_BLOCKS - 1) ? 1 : 0;
    }
    __syncthreads();
    if (!lastflag) return;

    // system-scope loads: bypass per-XCD L2 (writers fenced via threadfence)
    for (int i = tid; i < 2 * HIST_ELEMS; i += 256)
        h2[i] = __hip_atomic_load(&hist[i], __ATOMIC_RELAXED, __HIP_MEMORY_SCOPE_SYSTEM);
    __syncthreads();

    float accl = 0.0f;
    for (int nn = 0; nn < 2; ++nn) {
        const float* h = h2 + nn * HIST_ELEMS;
        {
            int r = tid >> 2, q = tid & 3;
            const float* hp = h + r * NBINS + q * 16;
            float sv = 0.0f;
            #pragma unroll
            for (int k = 0; k < 16; ++k) sv += hp[k];
            sv += __shfl_down(sv, 1, 64);
            sv += __shfl_down(sv, 2, 64);
            if (q == 0) rowsum[r] = sv;
        }
        {
            int c = tid & 63, g = tid >> 6;
            const float* hp = h + (g * 16) * NBINS + c;
            float sv = 0.0f;
            #pragma unroll
            for (int k = 0; k < 16; ++k) sv += hp[k * NBINS];
            colp[g * NBINS + c] = sv;
        }
        __syncthreads();
        if (tid < NBINS)
            colsum[tid] = colp[0 * NBINS + tid] + colp[1 * NBINS + tid] +
                          colp[2 * NBINS + tid] + colp[3 * NBINS + tid];
        __syncthreads();

        float tv = (tid < NBINS) ? rowsum[tid] : 0.0f;
        for (int off = 32; off > 0; off >>= 1) tv += __shfl_down(tv, off, 64);
        __syncthreads();
        if (lane == 0) buf[wave] = tv;
        __syncthreads();
        const float total = buf[0] + buf[1] + buf[2] + buf[3];
        const float inv = 1.0f / total;

        float ej = 0.0f;
        for (int i = tid; i < HIST_ELEMS; i += 256) {
            float p = h[i] * inv;
            ej += p * __logf(p + 1e-10f);
        }
        for (int off = 32; off > 0; off >>= 1) ej += __shfl_down(ej, off, 64);
        __syncthreads();
        if (lane == 0) buf[wave] = ej;
        __syncthreads();
        const float entj = -(buf[0] + buf[1] + buf[2] + buf[3]);

        float em = 0.0f;
        if (tid < NBINS) {
            float p = rowsum[tid] * inv;
            em = p * __logf(p + 1e-10f);
        } else if (tid < 2 * NBINS) {
            float p = colsum[tid - NBINS] * inv;
            em = p * __logf(p + 1e-10f);
        }
        for (int off = 32; off > 0; off >>= 1) em += __shfl_down(em, off, 64);
        __syncthreads();
        if (lane == 0) buf[wave] = em;
        __syncthreads();
        const float ents = -(buf[0] + buf[1] + buf[2] + buf[3]);

        accl += ents / entj;
        __syncthreads();
    }
    if (tid == 0) out[0] = -0.5f * accl;
}

extern "C" void kernel_launch(void* const* d_in, const int* in_sizes, int n_in,
                              void* d_out, int out_size, void* d_ws, size_t ws_size,
                              hipStream_t stream) {
    const float* tar = (const float*)d_in[0];
    const float* src = (const float*)d_in[1];
    const int N = 2;
    const int P = in_sizes[0] / N;  // 884736

    float* pm = (float*)d_ws;
    unsigned* ctr = (unsigned*)((char*)d_ws + 2048);
    float* hist = (float*)((char*)d_ws + 4096);
    _Float16* bh = (_Float16*)((char*)d_ws + 36864);
    float* out = (float*)d_out;

    const size_t need = 36864 + (size_t)2 * GXN * HIST_ELEMS * sizeof(_Float16); // ~8.4 MB

    minmax_kernel<<<dim3(64, N, 2), 256, 0, stream>>>(tar, src, pm, ctr, hist, P);
    if (ws_size >= need) {
        mfma_hist_kernel<1><<<dim3(GXN, N), 256, 0, stream>>>(tar, src, pm, bh, hist, P);
        reduce_finalize_kernel<<<RED_BLOCKS, 256, 0, stream>>>(bh, hist, ctr, out, 1);
    } else {
        mfma_hist_kernel<0><<<dim3(GXN, N), 256, 0, stream>>>(tar, src, pm, bh, hist, P);
        reduce_finalize_kernel<<<RED_BLOCKS, 256, 0, stream>>>(bh, hist, ctr, out, 0);
    }
}

// Round 9
// 131.972 us; speedup vs baseline: 2.5267x; 1.0017x over previous
//
#include <hip/hip_runtime.h>
#include <math.h>

#define NBINS 64
#define HIST_ELEMS (NBINS*NBINS)
#define PTS_PER_BLOCK 2304      // 384 blocks/n * 2304 = 884736 = P; grid 768 = 3/CU even
#define GXN 384                 // hist blocks per sample
#define CHUNKS 18               // per wave: 2304 / (4 waves * 32)
#define LSTRIDE 68              // col-major lh stride (b128 2-way banks = free)
// weight = exp2(-(u*SQK - b*SQK)^2); SQK = sqrt(8192/63^2*log2(e))
#define SQK 1.7256062f
#define RED_BLOCKS 128
#define TILES_PER_WAVE (GXN/4)  // 96
#define SMEM_FLOATS (2*PTS_PER_BLOCK + NBINS*LSTRIDE)   // 8960 floats = 35840 B

typedef float f4 __attribute__((ext_vector_type(4)));
typedef float f2 __attribute__((ext_vector_type(2)));
typedef float f32x4 __attribute__((ext_vector_type(4)));
typedef _Float16 half8 __attribute__((ext_vector_type(8)));
typedef int int4v __attribute__((ext_vector_type(4)));
typedef unsigned int u32x2 __attribute__((ext_vector_type(2)));

static __device__ __forceinline__ half8 pack8(const float* w) {
    int4v v;
    v[0] = __builtin_bit_cast(int, __builtin_amdgcn_cvt_pkrtz(w[0], w[1]));
    v[1] = __builtin_bit_cast(int, __builtin_amdgcn_cvt_pkrtz(w[2], w[3]));
    v[2] = __builtin_bit_cast(int, __builtin_amdgcn_cvt_pkrtz(w[4], w[5]));
    v[3] = __builtin_bit_cast(int, __builtin_amdgcn_cvt_pkrtz(w[6], w[7]));
    return __builtin_bit_cast(half8, v);
}

// packed-f32 math (gfx90a+): 2 f32 lanes per VALU issue
static __device__ __forceinline__ f2 pk_fma(f2 a, f2 b, f2 c) {
    f2 d;
    asm("v_pk_fma_f32 %0, %1, %2, %3" : "=v"(d) : "v"(a), "v"(b), "v"(c));
    return d;
}
static __device__ __forceinline__ f2 pk_mul(f2 a, f2 b) {
    f2 d;
    asm("v_pk_mul_f32 %0, %1, %2" : "=v"(d) : "v"(a), "v"(b));
    return d;
}
static __device__ __forceinline__ f2 pk_add(f2 a, f2 b) {
    f2 d;
    asm("v_pk_add_f32 %0, %1, %2" : "=v"(d) : "v"(a), "v"(b));
    return d;
}

// ws layout: pm[512] floats @0 | unsigned ctr @2048 | float hist[2][4096] @4096
//            | _Float16 bh[2*GXN][4096] @36864 (~6.33 MB)
__global__ __launch_bounds__(256) void minmax_kernel(const float* __restrict__ tar,
                                                     const float* __restrict__ src,
                                                     float* __restrict__ pm,
                                                     unsigned* __restrict__ ctr,
                                                     float* __restrict__ hist, int P) {
    const int b = blockIdx.x, n = blockIdx.y, t = blockIdx.z;
    const f4* x = (const f4*)((t == 0 ? tar : src) + (size_t)n * P);
    const int per = (P / 4) / 64;   // 3456 f4 per block
    float lmin = INFINITY, lmax = -INFINITY;
    for (int i = b * per + threadIdx.x; i < (b + 1) * per; i += 256) {
        f4 v = x[i];
        lmin = fminf(lmin, fminf(fminf(v[0], v[1]), fminf(v[2], v[3])));
        lmax = fmaxf(lmax, fmaxf(fmaxf(v[0], v[1]), fmaxf(v[2], v[3])));
    }
    for (int off = 32; off > 0; off >>= 1) {
        lmin = fminf(lmin, __shfl_down(lmin, off, 64));
        lmax = fmaxf(lmax, __shfl_down(lmax, off, 64));
    }
    __shared__ float smin[4], smax[4];
    const int lane = threadIdx.x & 63, wave = threadIdx.x >> 6;
    if (lane == 0) { smin[wave] = lmin; smax[wave] = lmax; }
    __syncthreads();
    if (threadIdx.x == 0) {
        pm[(n * 2 + t) * 64 + b] =
            fminf(fminf(smin[0], smin[1]), fminf(smin[2], smin[3]));
        pm[256 + (n * 2 + t) * 64 + b] =
            fmaxf(fmaxf(smax[0], smax[1]), fmaxf(smax[2], smax[3]));
    }
    // zero global hist (8192 floats over 256 blocks = 8 f4 each) + counter
    const int flat = b + 64 * n + 128 * t;   // 0..255
    f4* hz = (f4*)hist + flat * 8;
    const f4 z = {0.f, 0.f, 0.f, 0.f};
    if (threadIdx.x < 8) hz[threadIdx.x] = z;
    if (flat == 0 && threadIdx.x == 0) *ctr = 0u;
}

// Joint histogram as 64x64xP GEMM via MFMA f16 -- merge of the two verified
// variants: r1's schedule (GXN=384, uniform 18 chunks/wave, unroll 3 for
// cross-chunk ILP -- the r8 post-mortem isolated unroll-1 as the regression)
// + r8's register-lean weight math (streamed af, base+cm consts, bit-exact).
// launch_bounds(256,4): unified 60+64 acc = ~124 <= 128 cap, 64 spare regs
// for the unroll-3 pipeline.  LDS 35.8KB x 4 = 143KB <= 160 OK.
// Ledger: scatter dead (r3/4: ~3.25cyc/lane LDS RMW), col-split dead (r5),
// recurrence NaN (r6), unstaged dead (r7: 56us), wave-occupancy alone is NOT
// the bottleneck (r8: 4-wave tier, occ +6.6pp, dur +1.4us) -- ILP is.
// A[m][k]: m=lane&15 (+16*mt), k=quad*8+j ; B[k][n]: n=lane&15, k=quad*8+j
// C/D: col=lane&15, row=quad*4+reg -> col-major lh; output TRANSPOSED
// (MI loss is transpose-invariant).
template <int STAGED>
__global__ __launch_bounds__(256, 4) void mfma_hist_kernel(const float* __restrict__ tar,
                                                           const float* __restrict__ src,
                                                           const float* __restrict__ pm,
                                                           _Float16* __restrict__ bh,
                                                           float* __restrict__ hist,
                                                           int P) {
    const int n = blockIdx.y;
    const int bx = blockIdx.x;
    const int tid = threadIdx.x;
    const int lane = tid & 63, wave = tid >> 6;
    const int mlane = lane & 15, quad = lane >> 4;

    __shared__ float smem[SMEM_FLOATS];
    __shared__ float mmred[4];
    float* su_t = smem;
    float* su_s = smem + PTS_PER_BLOCK;
    float* lh = smem + 2 * PTS_PER_BLOCK;   // col-major: lh[col*LSTRIDE + row]

    // --- wave 0: reduce the 64 per-block minmax partials ---
    if (wave == 0) {
        float a = pm[(n * 2 + 0) * 64 + lane];
        float b = pm[256 + (n * 2 + 0) * 64 + lane];
        float c = pm[(n * 2 + 1) * 64 + lane];
        float d = pm[256 + (n * 2 + 1) * 64 + lane];
        for (int off = 32; off > 0; off >>= 1) {
            a = fminf(a, __shfl_down(a, off, 64));
            b = fmaxf(b, __shfl_down(b, off, 64));
            c = fminf(c, __shfl_down(c, off, 64));
            d = fmaxf(d, __shfl_down(d, off, 64));
        }
        if (lane == 0) { mmred[0] = a; mmred[1] = b; mmred[2] = c; mmred[3] = d; }
    }

    // --- stage raw inputs: 576 f4 per tensor, coalesced ---
    {
        const f4* tg = (const f4*)(tar + (size_t)n * P + (size_t)bx * PTS_PER_BLOCK);
        const f4* sg = (const f4*)(src + (size_t)n * P + (size_t)bx * PTS_PER_BLOCK);
        f4* st4 = (f4*)su_t;
        f4* ss4 = (f4*)su_s;
        #pragma unroll
        for (int k = 0; k < 2; ++k) {
            const int i = tid + k * 256;
            st4[i] = tg[i];
            ss4[i] = sg[i];
        }
        if (tid < 64) {
            const int i = 512 + tid;
            st4[i] = tg[i];
            ss4[i] = sg[i];
        }
    }
    __syncthreads();   // staging + mmred complete

    const float tmin = mmred[0], tmax = mmred[1];
    const float smin = mmred[2], smax = mmred[3];
    const float tk = 63.0f / (tmax - tmin + 1e-10f) * SQK;
    const float sk = 63.0f / (smax - smin + 1e-10f) * SQK;
    const f2 tkk = {tk, tk}, skk = {sk, sk};
    const float tb0 = -(tmin * tk + SQK * (float)mlane);
    const float sb0 = -(smin * sk + SQK * (float)mlane);
    const f2 tbase = {tb0, tb0};
    const f2 sbase = {sb0, sb0};
    f2 cmv[3];
    #pragma unroll
    for (int m = 0; m < 3; ++m) {
        const float c = -16.0f * SQK * (float)(m + 1);
        cmv[m] = {c, c};
    }

    f32x4 acc[4][4];
    #pragma unroll
    for (int a = 0; a < 4; ++a)
        #pragma unroll
        for (int b = 0; b < 4; ++b) acc[a][b] = (f32x4){0.f, 0.f, 0.f, 0.f};

    // --- compute: wave owns 576 points = 18 chunks of K=32, barrier-free ---
    const int kwbase = wave * (32 * CHUNKS) + quad * 8;
    #pragma unroll 3
    for (int c = 0; c < CHUNKS; ++c) {
        const int kbase = kwbase + c * 32;
        const f4* pt4 = (const f4*)&su_t[kbase];
        const f4* ps4 = (const f4*)&su_s[kbase];
        f4 ta = pt4[0], tb = pt4[1];
        f4 sa = ps4[0], sb = ps4[1];
        f2 et[4], es[4];
        et[0] = pk_fma((f2){ta[0], ta[1]}, tkk, tbase);
        et[1] = pk_fma((f2){ta[2], ta[3]}, tkk, tbase);
        et[2] = pk_fma((f2){tb[0], tb[1]}, tkk, tbase);
        et[3] = pk_fma((f2){tb[2], tb[3]}, tkk, tbase);
        es[0] = pk_fma((f2){sa[0], sa[1]}, skk, sbase);
        es[1] = pk_fma((f2){sa[2], sa[3]}, skk, sbase);
        es[2] = pk_fma((f2){sb[0], sb[1]}, skk, sbase);
        es[3] = pk_fma((f2){sb[2], sb[3]}, skk, sbase);

        half8 bf[4];
        #pragma unroll
        for (int nt = 0; nt < 4; ++nt) {
            float w[8];
            #pragma unroll
            for (int h = 0; h < 4; ++h) {
                f2 d = (nt == 0) ? es[h] : pk_add(es[h], cmv[nt - 1]);
                f2 s2 = pk_mul(d, d);
                w[2 * h]     = __builtin_amdgcn_exp2f(-s2[0]);
                w[2 * h + 1] = __builtin_amdgcn_exp2f(-s2[1]);
            }
            bf[nt] = pack8(w);
        }
        #pragma unroll
        for (int mt = 0; mt < 4; ++mt) {
            float w[8];
            #pragma unroll
            for (int h = 0; h < 4; ++h) {
                f2 d = (mt == 0) ? et[h] : pk_add(et[h], cmv[mt - 1]);
                f2 s2 = pk_mul(d, d);
                w[2 * h]     = __builtin_amdgcn_exp2f(-s2[0]);
                w[2 * h + 1] = __builtin_amdgcn_exp2f(-s2[1]);
            }
            half8 af = pack8(w);
            #pragma unroll
            for (int nt = 0; nt < 4; ++nt)
                acc[mt][nt] = __builtin_amdgcn_mfma_f32_16x16x32_f16(
                    af, bf[nt], acc[mt][nt], 0, 0, 0);
        }
    }

    // --- serial-wave non-atomic combine into col-major lh ---
    #pragma unroll
    for (int w = 0; w < 4; ++w) {
        if (wave == w) {
            #pragma unroll
            for (int nt = 0; nt < 4; ++nt)
                #pragma unroll
                for (int mt = 0; mt < 4; ++mt) {
                    f4* p = (f4*)&lh[(16 * nt + mlane) * LSTRIDE + 16 * mt + 4 * quad];
                    if (w == 0) {
                        *p = acc[mt][nt];
                    } else {
                        f4 v = *p;
                        v += acc[mt][nt];
                        *p = v;
                    }
                }
        }
        __syncthreads();
    }

    if (STAGED) {
        // compact col-major lh -> private dense 4096-entry f16 tile (no atomics)
        u32x2* dst = (u32x2*)(bh + ((size_t)n * GXN + bx) * HIST_ELEMS);
        #pragma unroll
        for (int k = 0; k < 4; ++k) {
            const int i4 = tid + k * 256;          // 0..1023, 4 f16 each
            const int c = i4 >> 4, r4 = (i4 & 15) * 4;
            f4 v = *(const f4*)&lh[c * LSTRIDE + r4];
            u32x2 o;
            o[0] = __builtin_bit_cast(unsigned int, __builtin_amdgcn_cvt_pkrtz(v[0], v[1]));
            o[1] = __builtin_bit_cast(unsigned int, __builtin_amdgcn_cvt_pkrtz(v[2], v[3]));
            dst[i4] = o;
        }
    } else {
        float* gh = hist + (size_t)n * HIST_ELEMS;
        for (int i = tid; i < HIST_ELEMS; i += 256) {
            const int c = i >> 6, r = i & 63;
            unsafeAtomicAdd(&gh[i], lh[c * LSTRIDE + r]);
        }
    }
}

// 128 blocks: each owns 64 hist elements; each wave sums 96 f16 tiles,
// LDS-combine, plain store -> hist.  Last-arriving block finalizes.
__global__ __launch_bounds__(256) void reduce_finalize_kernel(const _Float16* __restrict__ bh,
                                                              float* __restrict__ hist,
                                                              unsigned* __restrict__ ctr,
                                                              float* __restrict__ out,
                                                              int staged) {
    const int tid = threadIdx.x;
    const int lane = tid & 63, wave = tid >> 6;
    __shared__ float h2[2 * HIST_ELEMS];
    __shared__ float buf[4], rowsum[NBINS], colsum[NBINS], colp[4 * NBINS];
    __shared__ float part[4][64];
    __shared__ int lastflag;

    if (staged) {
        const int g = blockIdx.x * 64 + lane;   // 0..8191
        const int n = g >> 12, e = g & 4095;
        const _Float16* p = bh + (((size_t)(n * GXN + wave * TILES_PER_WAVE)) << 12) + e;
        float s = 0.0f;
        #pragma unroll 8
        for (int b = 0; b < TILES_PER_WAVE; ++b) s += (float)p[(size_t)b << 12];
        part[wave][lane] = s;
        __syncthreads();
        if (wave == 0)
            hist[g] = part[0][lane] + part[1][lane] + part[2][lane] + part[3][lane];
    }

    __threadfence();
    if (tid == 0) {
        unsigned old = atomicAdd(ctr, 1u);
        lastflag = (old == RED_BLOCKS - 1) ? 1 : 0;
    }
    __syncthreads();
    if (!lastflag) return;

    // system-scope loads: bypass per-XCD L2 (writers fenced via threadfence)
    for (int i = tid; i < 2 * HIST_ELEMS; i += 256)
        h2[i] = __hip_atomic_load(&hist[i], __ATOMIC_RELAXED, __HIP_MEMORY_SCOPE_SYSTEM);
    __syncthreads();

    float accl = 0.0f;
    for (int nn = 0; nn < 2; ++nn) {
        const float* h = h2 + nn * HIST_ELEMS;
        {
            int r = tid >> 2, q = tid & 3;
            const float* hp = h + r * NBINS + q * 16;
            float sv = 0.0f;
            #pragma unroll
            for (int k = 0; k < 16; ++k) sv += hp[k];
            sv += __shfl_down(sv, 1, 64);
            sv += __shfl_down(sv, 2, 64);
            if (q == 0) rowsum[r] = sv;
        }
        {
            int c = tid & 63, g = tid >> 6;
            const float* hp = h + (g * 16) * NBINS + c;
            float sv = 0.0f;
            #pragma unroll
            for (int k = 0; k < 16; ++k) sv += hp[k * NBINS];
            colp[g * NBINS + c] = sv;
        }
        __syncthreads();
        if (tid < NBINS)
            colsum[tid] = colp[0 * NBINS + tid] + colp[1 * NBINS + tid] +
                          colp[2 * NBINS + tid] + colp[3 * NBINS + tid];
        __syncthreads();

        float tv = (tid < NBINS) ? rowsum[tid] : 0.0f;
        for (int off = 32; off > 0; off >>= 1) tv += __shfl_down(tv, off, 64);
        __syncthreads();
        if (lane == 0) buf[wave] = tv;
        __syncthreads();
        const float total = buf[0] + buf[1] + buf[2] + buf[3];
        const float inv = 1.0f / total;

        float ej = 0.0f;
        for (int i = tid; i < HIST_ELEMS; i += 256) {
            float p = h[i] * inv;
            ej += p * __logf(p + 1e-10f);
        }
        for (int off = 32; off > 0; off >>= 1) ej += __shfl_down(ej, off, 64);
        __syncthreads();
        if (lane == 0) buf[wave] = ej;
        __syncthreads();
        const float entj = -(buf[0] + buf[1] + buf[2] + buf[3]);

        float em = 0.0f;
        if (tid < NBINS) {
            float p = rowsum[tid] * inv;
            em = p * __logf(p + 1e-10f);
        } else if (tid < 2 * NBINS) {
            float p = colsum[tid - NBINS] * inv;
            em = p * __logf(p + 1e-10f);
        }
        for (int off = 32; off > 0; off >>= 1) em += __shfl_down(em, off, 64);
        __syncthreads();
        if (lane == 0) buf[wave] = em;
        __syncthreads();
        const float ents = -(buf[0] + buf[1] + buf[2] + buf[3]);

        accl += ents / entj;
        __syncthreads();
    }
    if (tid == 0) out[0] = -0.5f * accl;
}

extern "C" void kernel_launch(void* const* d_in, const int* in_sizes, int n_in,
                              void* d_out, int out_size, void* d_ws, size_t ws_size,
                              hipStream_t stream) {
    const float* tar = (const float*)d_in[0];
    const float* src = (const float*)d_in[1];
    const int N = 2;
    const int P = in_sizes[0] / N;  // 884736

    float* pm = (float*)d_ws;
    unsigned* ctr = (unsigned*)((char*)d_ws + 2048);
    float* hist = (float*)((char*)d_ws + 4096);
    _Float16* bh = (_Float16*)((char*)d_ws + 36864);
    float* out = (float*)d_out;

    const size_t need = 36864 + (size_t)2 * GXN * HIST_ELEMS * sizeof(_Float16); // ~6.33 MB

    minmax_kernel<<<dim3(64, N, 2), 256, 0, stream>>>(tar, src, pm, ctr, hist, P);
    if (ws_size >= need) {
        mfma_hist_kernel<1><<<dim3(GXN, N), 256, 0, stream>>>(tar, src, pm, bh, hist, P);
        reduce_finalize_kernel<<<RED_BLOCKS, 256, 0, stream>>>(bh, hist, ctr, out, 1);
    } else {
        mfma_hist_kernel<0><<<dim3(GXN, N), 256, 0, stream>>>(tar, src, pm, bh, hist, P);
        reduce_finalize_kernel<<<RED_BLOCKS, 256, 0, stream>>>(bh, hist, ctr, out, 0);
    }
}